// Round 9
// baseline (279.054 us; speedup 1.0000x reference)
//
#include <hip/hip_runtime.h>
#include <math.h>

#define TDIM 512
#define DDIM 512
#define NTROWS 4096
#define MROWS 16384
#define EPSGN 1e-3f

typedef __attribute__((ext_vector_type(8))) short bf16x8;
typedef __attribute__((ext_vector_type(4))) float f32x4;
typedef __attribute__((ext_vector_type(8))) unsigned short us8;
typedef __attribute__((ext_vector_type(4))) unsigned short us4;

__device__ __forceinline__ unsigned short f2b(float f) {
  unsigned int u = __float_as_uint(f);
  return (unsigned short)((u + 0x7fffu + ((u >> 16) & 1u)) >> 16);
}
__device__ __forceinline__ float b2f(unsigned short h) {
  return __uint_as_float(((unsigned int)h) << 16);
}

#define GLOAD16(g, l)                                                                   \
  __builtin_amdgcn_global_load_lds((const __attribute__((address_space(1))) void*)(g),  \
                                   (__attribute__((address_space(3))) void*)(l), 16, 0, 0)

// ------- fused: fp32 -> raw bf16 convert + GroupNorm partial stats (+ Wz/W2 convert) -------
__global__ __launch_bounds__(256) void stats_cvt(const float* __restrict__ x0,
                                                 const float* __restrict__ x1,
                                                 unsigned short* __restrict__ o0,
                                                 unsigned short* __restrict__ o1,
                                                 float* __restrict__ p0,
                                                 float* __restrict__ p1,
                                                 const float* __restrict__ Wz,
                                                 const float* __restrict__ W2,
                                                 unsigned short* __restrict__ w16s) {
  if (blockIdx.y == 2) {
    const int bid = blockIdx.x;
    if (bid >= 256) return;
    const int c = bid * 256 + threadIdx.x;
    const int t = c >> 15;
    const int off = c & 32767;
    const float* s = t ? W2 : Wz;
    unsigned short* d = w16s + (size_t)(16 + t) * 262144;
    const float4 f0 = *(const float4*)(s + (size_t)off * 8);
    const float4 f1 = *(const float4*)(s + (size_t)off * 8 + 4);
    us8 v;
    v[0] = f2b(f0.x); v[1] = f2b(f0.y); v[2] = f2b(f0.z); v[3] = f2b(f0.w);
    v[4] = f2b(f1.x); v[5] = f2b(f1.y); v[6] = f2b(f1.z); v[7] = f2b(f1.w);
    *(us8*)(d + (size_t)off * 8) = v;
    return;
  }
  const float* x = blockIdx.y ? x1 : x0;
  unsigned short* o = blockIdx.y ? o1 : o0;
  float* part = blockIdx.y ? p1 : p0;
  const int blk = blockIdx.x;
  const int batch = blk >> 7;
  const int chunk = blk & 127;
  const size_t base = (size_t)blk * 32 * 512;
  const int tid = threadIdx.x;
  float s = 0.f, sq = 0.f;
#pragma unroll 4
  for (int it = 0; it < 8; ++it) {
    const size_t e = base + (size_t)it * 2048 + (size_t)tid * 8;
    const float4 f0 = *(const float4*)(x + e);
    const float4 f1 = *(const float4*)(x + e + 4);
    us8 v;
    v[0] = f2b(f0.x); v[1] = f2b(f0.y); v[2] = f2b(f0.z); v[3] = f2b(f0.w);
    v[4] = f2b(f1.x); v[5] = f2b(f1.y); v[6] = f2b(f1.z); v[7] = f2b(f1.w);
    *(us8*)(o + e) = v;
    s += f0.x + f0.y + f0.z + f0.w + f1.x + f1.y + f1.z + f1.w;
    sq += f0.x * f0.x + f0.y * f0.y + f0.z * f0.z + f0.w * f0.w +
          f1.x * f1.x + f1.y * f1.y + f1.z * f1.z + f1.w * f1.w;
  }
  const int wave = tid >> 6, lane = tid & 63;
#pragma unroll
  for (int of = 1; of < 16; of <<= 1) { s += __shfl_xor(s, of); sq += __shfl_xor(sq, of); }
  __shared__ float red[4][4][2];
  if ((lane & 15) == 0) { red[wave][lane >> 4][0] = s; red[wave][lane >> 4][1] = sq; }
  __syncthreads();
  if (tid < 4) {
    float S = 0.f, SQ = 0.f;
#pragma unroll
    for (int w = 0; w < 4; ++w) { S += red[w][tid][0]; SQ += red[w][tid][1]; }
    const int idx = (((batch << 2) | tid) << 7) | chunk;
    part[idx * 2] = S;
    part[idx * 2 + 1] = SQ;
  }
}

// ---------------- weight prep: per-batch GN-scaled weights + column corrections ------------
__global__ __launch_bounds__(256) void wprep(const float* __restrict__ Wq,
                                             const float* __restrict__ Wk,
                                             const float* __restrict__ Wv,
                                             const float* __restrict__ W1,
                                             const float* __restrict__ p0,
                                             const float* __restrict__ p1,
                                             unsigned short* __restrict__ w16s,
                                             float* __restrict__ corr) {
  const int y = blockIdx.y;
  const int w = y >> 2, b = y & 3;
  const float* W = (w == 0) ? Wq : (w == 1) ? Wk : (w == 2) ? Wv : W1;
  const float* part = (w == 0 || w == 3) ? p0 : p1;
  __shared__ float mrs[4][2];
  if (threadIdx.x < 4) {
    const float* p = part + (((b << 2) | threadIdx.x) << 7) * 2;
    float S = 0.f, SQ = 0.f;
    for (int c = 0; c < 128; ++c) { S += p[c * 2]; SQ += p[c * 2 + 1]; }
    const float inv = 1.f / (float)(NTROWS * 128);
    const float mu = S * inv;
    const float var = SQ * inv - mu * mu;
    const float rs = rsqrtf(var + EPSGN);
    mrs[threadIdx.x][0] = rs;
    mrs[threadIdx.x][1] = mu * rs;
  }
  __syncthreads();
  const int wave = threadIdx.x >> 6, lane = threadIdx.x & 63;
  const int n = blockIdx.x * 4 + wave;
  const int k = lane * 8;
  const int g = lane >> 4;
  const float rs = mrs[g][0], murs = mrs[g][1];
  const float4 f0 = *(const float4*)(W + (size_t)n * 512 + k);
  const float4 f1 = *(const float4*)(W + (size_t)n * 512 + k + 4);
  us8 v;
  v[0] = f2b(f0.x * rs); v[1] = f2b(f0.y * rs); v[2] = f2b(f0.z * rs); v[3] = f2b(f0.w * rs);
  v[4] = f2b(f1.x * rs); v[5] = f2b(f1.y * rs); v[6] = f2b(f1.z * rs); v[7] = f2b(f1.w * rs);
  *(us8*)(w16s + (size_t)((w << 2) | b) * 262144 + (size_t)n * 512 + k) = v;
  float t = (f0.x + f0.y + f0.z + f0.w + f1.x + f1.y + f1.z + f1.w) * murs;
#pragma unroll
  for (int of = 1; of < 64; of <<= 1) t += __shfl_xor(t, of);
  if (lane == 0) corr[(((w << 2) | b) << 9) | n] = t;
}

// ---------------- unified projection GEMMs (one launch, grid (128,8,2)) ----------------
__global__ __launch_bounds__(256) void gemm_all(const unsigned short* __restrict__ a16,
                                                const unsigned short* __restrict__ akv16,
                                                const unsigned short* __restrict__ w16s,
                                                const float* __restrict__ corr,
                                                unsigned short* __restrict__ q16,
                                                unsigned short* __restrict__ h16,
                                                unsigned short* __restrict__ k16,
                                                unsigned short* __restrict__ vTb,
                                                const float* __restrict__ b1,
                                                float* __restrict__ part_q,
                                                float* __restrict__ part_k,
                                                float* __restrict__ sk) {
  __shared__ __align__(16) unsigned short As[128 * 64];
  __shared__ __align__(16) unsigned short Bs[128 * 64];
  __shared__ float red[8];
  const int tid = threadIdx.x;
  const int wave = tid >> 6, lane = tid & 63;
  const int bm = blockIdx.x << 7;
  const int batch = blockIdx.x >> 5;
  const int z = blockIdx.z;
  const bool first = blockIdx.y < 4;
  const int widx = z ? (first ? 1 : 2) : (first ? 0 : 3);
  const unsigned short* A = z ? akv16 : a16;
  const unsigned short* B = w16s + (size_t)262144 * ((widx << 2) | batch);
  const int bnl = (blockIdx.y & 3) << 7;
  const int wr = (wave >> 1) << 6;
  const int wc = (wave & 1) << 6;
  const int lr = lane & 15, lg = lane >> 4;

  f32x4 acc[4][4] = {};
  const int srow = lane >> 3;
  const int sslot = (lane & 7) ^ srow;

  for (int k0 = 0; k0 < 512; k0 += 64) {
    __syncthreads();
#pragma unroll
    for (int i = 0; i < 4; ++i) {
      const int ci = wave * 4 + i;
      const int row = ci * 8 + srow;
      GLOAD16(A + (size_t)(bm + row) * 512 + k0 + sslot * 8, (char*)As + ci * 1024);
      GLOAD16(B + (size_t)(bnl + row) * 512 + k0 + sslot * 8, (char*)Bs + ci * 1024);
    }
    __syncthreads();
#pragma unroll
    for (int kk = 0; kk < 64; kk += 32) {
      bf16x8 af[4], bfr[4];
#pragma unroll
      for (int i = 0; i < 4; ++i) {
        const int row = wr + i * 16 + lr;
        af[i] = *(const bf16x8*)&As[row * 64 + ((((kk >> 3) + lg) ^ (row & 7)) << 3)];
      }
#pragma unroll
      for (int j = 0; j < 4; ++j) {
        const int row = wc + j * 16 + lr;
        bfr[j] = *(const bf16x8*)&Bs[row * 64 + ((((kk >> 3) + lg) ^ (row & 7)) << 3)];
      }
#pragma unroll
      for (int i = 0; i < 4; ++i)
#pragma unroll
        for (int j = 0; j < 4; ++j)
          acc[i][j] = __builtin_amdgcn_mfma_f32_16x16x32_bf16(af[i], bfr[j], acc[i][j], 0, 0, 0);
    }
  }

  {
    const float* cb = corr + (((widx << 2) | batch) << 9);
    float cj[4];
#pragma unroll
    for (int j = 0; j < 4; ++j) cj[j] = cb[bnl + wc + j * 16 + lr];
#pragma unroll
    for (int i = 0; i < 4; ++i)
#pragma unroll
      for (int j = 0; j < 4; ++j)
#pragma unroll
        for (int r = 0; r < 4; ++r) acc[i][j][r] -= cj[j];
  }

  if (first) {
    unsigned short* C0 = z ? k16 : q16;
#pragma unroll
    for (int i = 0; i < 4; ++i) {
      const int row0 = bm + wr + i * 16 + lg * 4;
#pragma unroll
      for (int j = 0; j < 4; ++j) {
        const int col = bnl + wc + j * 16 + lr;
#pragma unroll
        for (int r = 0; r < 4; ++r)
          C0[(size_t)(row0 + r) * 512 + col] = f2b(acc[i][j][r]);
      }
    }
    float s = 0.f, sq = 0.f;
#pragma unroll
    for (int i = 0; i < 4; ++i)
#pragma unroll
      for (int j = 0; j < 4; ++j)
#pragma unroll
        for (int r = 0; r < 4; ++r) { const float v = acc[i][j][r]; s += v; sq += v * v; }
#pragma unroll
    for (int o = 32; o > 0; o >>= 1) { s += __shfl_xor(s, o); sq += __shfl_xor(sq, o); }
    if (lane == 0) { red[wave * 2] = s; red[wave * 2 + 1] = sq; }
    __syncthreads();
    if (tid == 0) {
      float* part = z ? part_k : part_q;
      const float S = red[0] + red[2] + red[4] + red[6];
      const float SQ = red[1] + red[3] + red[5] + red[7];
      const int slot = blockIdx.x & 31, g = blockIdx.y;
      const int idx = ((((batch << 2) | g) << 5) | slot) << 1;
      part[idx] = S;
      part[idx + 1] = SQ;
    }
    if (z) {
      const int head = (bnl >> 6) + (wave & 1);
#pragma unroll
      for (int i = 0; i < 4; ++i) {
#pragma unroll
        for (int r = 0; r < 4; ++r) {
          float t = acc[i][0][r] + acc[i][1][r] + acc[i][2][r] + acc[i][3][r];
#pragma unroll
          for (int o = 1; o < 16; o <<= 1) t += __shfl_xor(t, o);
          if (lr == 0)
            sk[(size_t)(bm + wr + i * 16 + lg * 4 + r) * 8 + head] = t;
        }
      }
    }
  } else if (z == 0) {
#pragma unroll
    for (int i = 0; i < 4; ++i) {
      const int row0 = bm + wr + i * 16 + lg * 4;
#pragma unroll
      for (int j = 0; j < 4; ++j) {
        const int col = bnl + wc + j * 16 + lr;
        const float bb = b1[col];
#pragma unroll
        for (int r = 0; r < 4; ++r) {
          float v = acc[i][j][r] + bb;
          v = v > 0.f ? v : 0.01f * v;
          h16[(size_t)(row0 + r) * 512 + col] = f2b(v);
        }
      }
    }
  } else {
#pragma unroll
    for (int i = 0; i < 4; ++i) {
      const int row0 = bm + wr + i * 16 + lg * 4;
#pragma unroll
      for (int j = 0; j < 4; ++j) {
        const int col = bnl + wc + j * 16 + lr;
        us4 pk;
#pragma unroll
        for (int r = 0; r < 4; ++r) pk[r] = f2b(acc[i][j][r]);
        *(us4*)&vTb[((size_t)(row0 >> 9) * 512 + col) * 512 + (row0 & 511)] = pk;
      }
    }
  }
}

// ---------------- final GEMM: out = [ao|h1](K=1024) @ [Wz|W2]^T + bz+b2 + in_f(bf16) -------
__global__ __launch_bounds__(256) void gemm_final(const unsigned short* __restrict__ A0,
                                                  const unsigned short* __restrict__ A1,
                                                  const unsigned short* __restrict__ B0,
                                                  const unsigned short* __restrict__ B1,
                                                  float* __restrict__ Cf,
                                                  const float* __restrict__ bias0,
                                                  const float* __restrict__ bias1,
                                                  const unsigned short* __restrict__ init16) {
  __shared__ __align__(16) unsigned short As[128 * 64];
  __shared__ __align__(16) unsigned short Bs[128 * 64];
  const int tid = threadIdx.x;
  const int wave = tid >> 6, lane = tid & 63;
  const int bm = blockIdx.x << 7, bn = blockIdx.y << 7;
  const int wr = (wave >> 1) << 6;
  const int wc = (wave & 1) << 6;
  const int lr = lane & 15, lg = lane >> 4;

  f32x4 acc[4][4] = {};
  const int srow = lane >> 3;
  const int sslot = (lane & 7) ^ srow;

  for (int k0 = 0; k0 < 1024; k0 += 64) {
    const unsigned short* Ab = (k0 < 512) ? A0 : A1;
    const unsigned short* Bb = (k0 < 512) ? B0 : B1;
    const int kl = k0 & 511;
    __syncthreads();
#pragma unroll
    for (int i = 0; i < 4; ++i) {
      const int ci = wave * 4 + i;
      const int row = ci * 8 + srow;
      GLOAD16(Ab + (size_t)(bm + row) * 512 + kl + sslot * 8, (char*)As + ci * 1024);
      GLOAD16(Bb + (size_t)(bn + row) * 512 + kl + sslot * 8, (char*)Bs + ci * 1024);
    }
    __syncthreads();
#pragma unroll
    for (int kk = 0; kk < 64; kk += 32) {
      bf16x8 af[4], bfr[4];
#pragma unroll
      for (int i = 0; i < 4; ++i) {
        const int row = wr + i * 16 + lr;
        af[i] = *(const bf16x8*)&As[row * 64 + ((((kk >> 3) + lg) ^ (row & 7)) << 3)];
      }
#pragma unroll
      for (int j = 0; j < 4; ++j) {
        const int row = wc + j * 16 + lr;
        bfr[j] = *(const bf16x8*)&Bs[row * 64 + ((((kk >> 3) + lg) ^ (row & 7)) << 3)];
      }
#pragma unroll
      for (int i = 0; i < 4; ++i)
#pragma unroll
        for (int j = 0; j < 4; ++j)
          acc[i][j] = __builtin_amdgcn_mfma_f32_16x16x32_bf16(af[i], bfr[j], acc[i][j], 0, 0, 0);
    }
  }

#pragma unroll
  for (int i = 0; i < 4; ++i) {
    const int row0 = bm + wr + i * 16 + lg * 4;
#pragma unroll
    for (int j = 0; j < 4; ++j) {
      const int col = bn + wc + j * 16 + lr;
      const float bb = bias0[col] + bias1[col];
#pragma unroll
      for (int r = 0; r < 4; ++r) {
        const size_t o = (size_t)(row0 + r) * 512 + col;
        Cf[o] = acc[i][j][r] + bb + b2f(init16[o]);
      }
    }
  }
}

// ------- fused attention: 44KB LDS (3 blocks/CU), streamed 128-tiles, bf16 P cache ---------
// sc/pc slot s (0..7): k = (s>>1)*128 + w*32 + (s&1)*16 + lr
__global__ __launch_bounds__(256, 3) void attn_fused(const unsigned short* __restrict__ q16,
                                                     const unsigned short* __restrict__ k16,
                                                     const unsigned short* __restrict__ vT,
                                                     const float* __restrict__ part_q,
                                                     const float* __restrict__ part_k,
                                                     const float* __restrict__ sk,
                                                     float* __restrict__ aw,
                                                     unsigned short* __restrict__ ao16) {
  __shared__ __align__(16) unsigned short Qs[64 * 64];    // 8 KB
  __shared__ __align__(16) unsigned short KVt[128 * 64];  // 16 KB: K tile [128k][64c] / V tile [64d][128k]
  __shared__ __align__(16) unsigned short Ps[64 * 128];   // 16 KB
  __shared__ float WM[4][64];
  __shared__ float WS[4][64];
  __shared__ float sk_lds[512];
  __shared__ float cst[2];

  const int bid = blockIdx.x;
  const int q0 = blockIdx.y << 6;
  const int h = bid & 7;
  const int b = bid >> 6;
  const int tid = threadIdx.x;
  const int w = tid >> 6, lane = tid & 63;
  const int lr = lane & 15, lg = lane >> 4;
  const int srow = lane >> 3;
  const int sslot = (lane & 7) ^ srow;

  const size_t hb = (size_t)(bid >> 3) * (512 * 512);
  const unsigned short* Qg = q16 + hb + h * 64;
  const unsigned short* Kg = k16 + hb + h * 64;
  const unsigned short* Vg = vT + hb + (size_t)h * 64 * 512;

  if (tid == 0) {
    const int pbase = (((b << 2) | (h >> 1)) << 6);
    const float* pq = part_q + pbase;
    const float* pk = part_k + pbase;
    float Sq = 0.f, SQq = 0.f, Sk = 0.f, SQk = 0.f;
    for (int c = 0; c < 32; ++c) {
      Sq += pq[c * 2]; SQq += pq[c * 2 + 1];
      Sk += pk[c * 2]; SQk += pk[c * 2 + 1];
    }
    const float inv = 1.f / (float)(NTROWS * 128);
    const float muq = Sq * inv, vq = SQq * inv - muq * muq;
    const float muk = Sk * inv, vk = SQk * inv - muk * muk;
    const float a = rsqrtf(vq + EPSGN) * rsqrtf(vk + EPSGN) * 0.125f;
    cst[0] = a;
    cst[1] = a * muq;
  }
  {
    const float* skg = sk + (size_t)(bid >> 3) * 512 * 8 + h;
    for (int j = tid; j < 512; j += 256) sk_lds[j] = skg[(size_t)j * 8];
  }

#pragma unroll
  for (int it = 0; it < 2; ++it) {  // stage Q 64x64 async
    const int ci = w * 2 + it;
    const int row = ci * 8 + srow;
    GLOAD16(Qg + (size_t)(q0 + row) * 512 + sslot * 8, (char*)Qs + ci * 1024);
  }

  // ---- QK^T: stream K in four 128-row tiles (single 16KB buffer) ----
  f32x4 sc[4][8] = {};
#pragma unroll
  for (int t = 0; t < 4; ++t) {
    __syncthreads();  // previous tile consumed (and sk_lds/cst published at t=0)
#pragma unroll
    for (int i = 0; i < 4; ++i) {
      const int ci = w * 4 + i;
      const int row = ci * 8 + srow;
      GLOAD16(Kg + (size_t)(t * 128 + row) * 512 + sslot * 8, (char*)KVt + ci * 1024);
    }
    __syncthreads();  // tile (and Qs at t=0) ready
#pragma unroll
    for (int kk = 0; kk < 64; kk += 32) {
      bf16x8 aq[4];
#pragma unroll
      for (int qf = 0; qf < 4; ++qf) {
        const int row = qf * 16 + lr;
        aq[qf] = *(const bf16x8*)&Qs[row * 64 + ((((kk >> 3) + lg) ^ (row & 7)) << 3)];
      }
#pragma unroll
      for (int kf = 0; kf < 2; ++kf) {
        const int rl = w * 32 + kf * 16 + lr;
        const bf16x8 bk = *(const bf16x8*)&KVt[rl * 64 + ((((kk >> 3) + lg) ^ (rl & 7)) << 3)];
#pragma unroll
        for (int qf = 0; qf < 4; ++qf)
          sc[qf][t * 2 + kf] =
              __builtin_amdgcn_mfma_f32_16x16x32_bf16(aq[qf], bk, sc[qf][t * 2 + kf], 0, 0, 0);
      }
    }
  }

  // ---- GN correction: logit = a*S - a*mu_q*Sk[col] ----
  const float aSc = cst[0], cmu = cst[1];
#pragma unroll
  for (int qf = 0; qf < 4; ++qf)
#pragma unroll
    for (int s = 0; s < 8; ++s) {
      const int k = ((s >> 1) << 7) + w * 32 + ((s & 1) << 4) + lr;
      const float corr = cmu * sk_lds[k];
#pragma unroll
      for (int r = 0; r < 4; ++r) sc[qf][s][r] = aSc * sc[qf][s][r] - corr;
    }

  // ---- softmax ----
  float Mv[4][4];
#pragma unroll
  for (int qf = 0; qf < 4; ++qf)
#pragma unroll
    for (int r = 0; r < 4; ++r) {
      float m = sc[qf][0][r];
#pragma unroll
      for (int kf = 1; kf < 8; ++kf) m = fmaxf(m, sc[qf][kf][r]);
#pragma unroll
      for (int o = 1; o < 16; o <<= 1) m = fmaxf(m, __shfl_xor(m, o));
      Mv[qf][r] = m;
    }
  if (lr == 0) {
#pragma unroll
    for (int qf = 0; qf < 4; ++qf)
#pragma unroll
      for (int r = 0; r < 4; ++r) WM[w][qf * 16 + lg * 4 + r] = Mv[qf][r];
  }
  __syncthreads();
#pragma unroll
  for (int qf = 0; qf < 4; ++qf)
#pragma unroll
    for (int r = 0; r < 4; ++r) {
      const int q = qf * 16 + lg * 4 + r;
      Mv[qf][r] = fmaxf(fmaxf(WM[0][q], WM[1][q]), fmaxf(WM[2][q], WM[3][q]));
    }
  float sl[4][4] = {};
#pragma unroll
  for (int qf = 0; qf < 4; ++qf)
#pragma unroll
    for (int kf = 0; kf < 8; ++kf) {
      f32x4 v = sc[qf][kf];
#pragma unroll
      for (int r = 0; r < 4; ++r) {
        const float e = __expf(v[r] - Mv[qf][r]);
        v[r] = e;
        sl[qf][r] += e;
      }
      sc[qf][kf] = v;
    }
#pragma unroll
  for (int qf = 0; qf < 4; ++qf)
#pragma unroll
    for (int r = 0; r < 4; ++r) {
      float s = sl[qf][r];
#pragma unroll
      for (int o = 1; o < 16; o <<= 1) s += __shfl_xor(s, o);
      sl[qf][r] = s;
    }
  if (lr == 0) {
#pragma unroll
    for (int qf = 0; qf < 4; ++qf)
#pragma unroll
      for (int r = 0; r < 4; ++r) WS[w][qf * 16 + lg * 4 + r] = sl[qf][r];
  }
  __syncthreads();

  // ---- normalize + fp32 P-write (nontemporal) + pack to bf16 (frees sc) ----
  us4 pc[4][8];
  float* AWp = aw + ((size_t)bid * 512 + q0) * 512;
#pragma unroll
  for (int qf = 0; qf < 4; ++qf) {
    float inv[4];
#pragma unroll
    for (int r = 0; r < 4; ++r) {
      const int q = qf * 16 + lg * 4 + r;
      inv[r] = 1.f / (WS[0][q] + WS[1][q] + WS[2][q] + WS[3][q]);
    }
#pragma unroll
    for (int s = 0; s < 8; ++s) {
      const int k = ((s >> 1) << 7) + w * 32 + ((s & 1) << 4) + lr;
#pragma unroll
      for (int r = 0; r < 4; ++r) {
        const float v = sc[qf][s][r] * inv[r];
        __builtin_nontemporal_store(v, &AWp[(size_t)(qf * 16 + lg * 4 + r) * 512 + k]);
        pc[qf][s][r] = f2b(v);
      }
    }
  }

  // ---- PV: stream V + P in four 128-k tiles (single buffers) ----
  f32x4 accO[4] = {};
#pragma unroll
  for (int t = 0; t < 4; ++t) {
    __syncthreads();  // previous tile consumed (t=0: QK reads of KVt long done)
#pragma unroll
    for (int i = 0; i < 4; ++i) {  // stage V tile t as [64 d][128 k]
      const int ci = w * 4 + i;
      const int row = ci * 4 + (lane >> 4);
      const int s = lane & 15;
      GLOAD16(Vg + (size_t)row * 512 + t * 128 + ((s ^ (row & 7)) << 3),
              (char*)KVt + ci * 1024);
    }
#pragma unroll
    for (int qf = 0; qf < 4; ++qf)  // stage P tile t (bf16, swizzled)
#pragma unroll
      for (int r = 0; r < 4; ++r) {
        const int q = qf * 16 + lg * 4 + r;
#pragma unroll
        for (int kf = 0; kf < 2; ++kf) {
          const int kl = w * 32 + kf * 16 + lr;
          Ps[q * 128 + (((kl >> 3) ^ (q & 7)) << 3) + (kl & 7)] = pc[qf][t * 2 + kf][r];
        }
      }
    __syncthreads();  // V tile (vmcnt) + P tile (lgkm) ready
#pragma unroll
    for (int ks = 0; ks < 128; ks += 32) {
      const int q = w * 16 + lr;
      const bf16x8 af = *(const bf16x8*)&Ps[q * 128 + ((((ks >> 3) + lg) ^ (q & 7)) << 3)];
#pragma unroll
      for (int df = 0; df < 4; ++df) {
        const int vrow = df * 16 + lr;
        const bf16x8 vb =
            *(const bf16x8*)&KVt[vrow * 128 + ((((ks >> 3) + lg) ^ (vrow & 7)) << 3)];
        accO[df] = __builtin_amdgcn_mfma_f32_16x16x32_bf16(af, vb, accO[df], 0, 0, 0);
      }
    }
  }

  const int growb = (bid >> 3) * 512 + q0 + w * 16 + lg * 4;
#pragma unroll
  for (int df = 0; df < 4; ++df)
#pragma unroll
    for (int r = 0; r < 4; ++r)
      ao16[(size_t)(growb + r) * 512 + h * 64 + df * 16 + lr] = f2b(accO[df][r]);
}

// ---------------- launcher ----------------
extern "C" void kernel_launch(void* const* d_in, const int* in_sizes, int n_in,
                              void* d_out, int out_size, void* d_ws, size_t ws_size,
                              hipStream_t stream) {
  const float* in_f = (const float*)d_in[1];
  const float* in_fkv = (const float*)d_in[2];
  const float* Wq = (const float*)d_in[3];
  const float* Wk = (const float*)d_in[4];
  const float* Wv = (const float*)d_in[5];
  const float* Wz = (const float*)d_in[6];
  const float* bz = (const float*)d_in[7];
  const float* W1 = (const float*)d_in[8];
  const float* b1 = (const float*)d_in[9];
  const float* W2 = (const float*)d_in[10];
  const float* b2 = (const float*)d_in[11];

  float* out_f = (float*)d_out;
  float* attw = out_f + (size_t)MROWS * DDIM;

  const size_t TSB = (size_t)MROWS * DDIM;
  unsigned short* us = (unsigned short*)d_ws;
  unsigned short* a16 = us;
  unsigned short* akv16 = us + TSB;
  unsigned short* q16 = us + 2 * TSB;
  unsigned short* k16 = us + 3 * TSB;
  unsigned short* h16 = us + 4 * TSB;
  unsigned short* ao16 = us + 5 * TSB;
  unsigned short* vT = us + 6 * TSB;
  unsigned short* w16s = us + 7 * TSB;
  float* fbase = (float*)(us + 7 * TSB + 18 * 262144);
  float* p0 = fbase;
  float* p1 = fbase + 4096;
  float* part_q = fbase + 8192;
  float* part_k = fbase + 9216;
  float* corr = fbase + 10240;
  float* sk = fbase + 18432;

  stats_cvt<<<dim3(512, 3), 256, 0, stream>>>(in_f, in_fkv, a16, akv16, p0, p1, Wz, W2, w16s);
  wprep<<<dim3(128, 16), 256, 0, stream>>>(Wq, Wk, Wv, W1, p0, p1, w16s, corr);
  gemm_all<<<dim3(128, 8, 2), 256, 0, stream>>>(a16, akv16, w16s, corr, q16, h16, k16, vT, b1,
                                                part_q, part_k, sk);
  attn_fused<<<dim3(256, 8), 256, 0, stream>>>(q16, k16, vT, part_q, part_k, sk, attw, ao16);
  gemm_final<<<dim3(128, 4), 256, 0, stream>>>(ao16, h16, w16s + 16 * 262144,
                                               w16s + 17 * 262144, out_f, bz, b2, a16);
}

// Round 10
// 267.284 us; speedup vs baseline: 1.0440x; 1.0440x over previous
//
#include <hip/hip_runtime.h>
#include <math.h>

#define TDIM 512
#define DDIM 512
#define NTROWS 4096
#define MROWS 16384
#define EPSGN 1e-3f

typedef __attribute__((ext_vector_type(8))) short bf16x8;
typedef __attribute__((ext_vector_type(4))) float f32x4;
typedef __attribute__((ext_vector_type(8))) unsigned short us8;
typedef __attribute__((ext_vector_type(4))) unsigned short us4;

__device__ __forceinline__ unsigned short f2b(float f) {
  unsigned int u = __float_as_uint(f);
  return (unsigned short)((u + 0x7fffu + ((u >> 16) & 1u)) >> 16);
}
__device__ __forceinline__ float b2f(unsigned short h) {
  return __uint_as_float(((unsigned int)h) << 16);
}

#define GLOAD16(g, l)                                                                   \
  __builtin_amdgcn_global_load_lds((const __attribute__((address_space(1))) void*)(g),  \
                                   (__attribute__((address_space(3))) void*)(l), 16, 0, 0)

// ------- fused: fp32 -> raw bf16 convert + GroupNorm partial stats (+ Wz/W2 convert) -------
__global__ __launch_bounds__(256) void stats_cvt(const float* __restrict__ x0,
                                                 const float* __restrict__ x1,
                                                 unsigned short* __restrict__ o0,
                                                 unsigned short* __restrict__ o1,
                                                 float* __restrict__ p0,
                                                 float* __restrict__ p1,
                                                 const float* __restrict__ Wz,
                                                 const float* __restrict__ W2,
                                                 unsigned short* __restrict__ w16s) {
  if (blockIdx.y == 2) {
    const int bid = blockIdx.x;
    if (bid >= 256) return;
    const int c = bid * 256 + threadIdx.x;
    const int t = c >> 15;
    const int off = c & 32767;
    const float* s = t ? W2 : Wz;
    unsigned short* d = w16s + (size_t)(16 + t) * 262144;
    const float4 f0 = *(const float4*)(s + (size_t)off * 8);
    const float4 f1 = *(const float4*)(s + (size_t)off * 8 + 4);
    us8 v;
    v[0] = f2b(f0.x); v[1] = f2b(f0.y); v[2] = f2b(f0.z); v[3] = f2b(f0.w);
    v[4] = f2b(f1.x); v[5] = f2b(f1.y); v[6] = f2b(f1.z); v[7] = f2b(f1.w);
    *(us8*)(d + (size_t)off * 8) = v;
    return;
  }
  const float* x = blockIdx.y ? x1 : x0;
  unsigned short* o = blockIdx.y ? o1 : o0;
  float* part = blockIdx.y ? p1 : p0;
  const int blk = blockIdx.x;
  const int batch = blk >> 7;
  const int chunk = blk & 127;
  const size_t base = (size_t)blk * 32 * 512;
  const int tid = threadIdx.x;
  float s = 0.f, sq = 0.f;
#pragma unroll 4
  for (int it = 0; it < 8; ++it) {
    const size_t e = base + (size_t)it * 2048 + (size_t)tid * 8;
    const float4 f0 = *(const float4*)(x + e);
    const float4 f1 = *(const float4*)(x + e + 4);
    us8 v;
    v[0] = f2b(f0.x); v[1] = f2b(f0.y); v[2] = f2b(f0.z); v[3] = f2b(f0.w);
    v[4] = f2b(f1.x); v[5] = f2b(f1.y); v[6] = f2b(f1.z); v[7] = f2b(f1.w);
    *(us8*)(o + e) = v;
    s += f0.x + f0.y + f0.z + f0.w + f1.x + f1.y + f1.z + f1.w;
    sq += f0.x * f0.x + f0.y * f0.y + f0.z * f0.z + f0.w * f0.w +
          f1.x * f1.x + f1.y * f1.y + f1.z * f1.z + f1.w * f1.w;
  }
  const int wave = tid >> 6, lane = tid & 63;
#pragma unroll
  for (int of = 1; of < 16; of <<= 1) { s += __shfl_xor(s, of); sq += __shfl_xor(sq, of); }
  __shared__ float red[4][4][2];
  if ((lane & 15) == 0) { red[wave][lane >> 4][0] = s; red[wave][lane >> 4][1] = sq; }
  __syncthreads();
  if (tid < 4) {
    float S = 0.f, SQ = 0.f;
#pragma unroll
    for (int w = 0; w < 4; ++w) { S += red[w][tid][0]; SQ += red[w][tid][1]; }
    const int idx = (((batch << 2) | tid) << 7) | chunk;
    part[idx * 2] = S;
    part[idx * 2 + 1] = SQ;
  }
}

// ---------------- weight prep: per-batch GN-scaled weights + column corrections ------------
__global__ __launch_bounds__(256) void wprep(const float* __restrict__ Wq,
                                             const float* __restrict__ Wk,
                                             const float* __restrict__ Wv,
                                             const float* __restrict__ W1,
                                             const float* __restrict__ p0,
                                             const float* __restrict__ p1,
                                             unsigned short* __restrict__ w16s,
                                             float* __restrict__ corr) {
  const int y = blockIdx.y;
  const int w = y >> 2, b = y & 3;
  const float* W = (w == 0) ? Wq : (w == 1) ? Wk : (w == 2) ? Wv : W1;
  const float* part = (w == 0 || w == 3) ? p0 : p1;
  __shared__ float mrs[4][2];
  if (threadIdx.x < 4) {
    const float* p = part + (((b << 2) | threadIdx.x) << 7) * 2;
    float S = 0.f, SQ = 0.f;
    for (int c = 0; c < 128; ++c) { S += p[c * 2]; SQ += p[c * 2 + 1]; }
    const float inv = 1.f / (float)(NTROWS * 128);
    const float mu = S * inv;
    const float var = SQ * inv - mu * mu;
    const float rs = rsqrtf(var + EPSGN);
    mrs[threadIdx.x][0] = rs;
    mrs[threadIdx.x][1] = mu * rs;
  }
  __syncthreads();
  const int wave = threadIdx.x >> 6, lane = threadIdx.x & 63;
  const int n = blockIdx.x * 4 + wave;
  const int k = lane * 8;
  const int g = lane >> 4;
  const float rs = mrs[g][0], murs = mrs[g][1];
  const float4 f0 = *(const float4*)(W + (size_t)n * 512 + k);
  const float4 f1 = *(const float4*)(W + (size_t)n * 512 + k + 4);
  us8 v;
  v[0] = f2b(f0.x * rs); v[1] = f2b(f0.y * rs); v[2] = f2b(f0.z * rs); v[3] = f2b(f0.w * rs);
  v[4] = f2b(f1.x * rs); v[5] = f2b(f1.y * rs); v[6] = f2b(f1.z * rs); v[7] = f2b(f1.w * rs);
  *(us8*)(w16s + (size_t)((w << 2) | b) * 262144 + (size_t)n * 512 + k) = v;
  float t = (f0.x + f0.y + f0.z + f0.w + f1.x + f1.y + f1.z + f1.w) * murs;
#pragma unroll
  for (int of = 1; of < 64; of <<= 1) t += __shfl_xor(t, of);
  if (lane == 0) corr[(((w << 2) | b) << 9) | n] = t;
}

// ---------------- unified projection GEMMs (one launch, grid (128,8,2)) ----------------
__global__ __launch_bounds__(256) void gemm_all(const unsigned short* __restrict__ a16,
                                                const unsigned short* __restrict__ akv16,
                                                const unsigned short* __restrict__ w16s,
                                                const float* __restrict__ corr,
                                                unsigned short* __restrict__ q16,
                                                unsigned short* __restrict__ h16,
                                                unsigned short* __restrict__ k16,
                                                unsigned short* __restrict__ vTb,
                                                const float* __restrict__ b1,
                                                float* __restrict__ part_q,
                                                float* __restrict__ part_k,
                                                float* __restrict__ sk) {
  __shared__ __align__(16) unsigned short As[128 * 64];
  __shared__ __align__(16) unsigned short Bs[128 * 64];
  __shared__ float red[8];
  const int tid = threadIdx.x;
  const int wave = tid >> 6, lane = tid & 63;
  const int bm = blockIdx.x << 7;
  const int batch = blockIdx.x >> 5;
  const int z = blockIdx.z;
  const bool first = blockIdx.y < 4;
  const int widx = z ? (first ? 1 : 2) : (first ? 0 : 3);
  const unsigned short* A = z ? akv16 : a16;
  const unsigned short* B = w16s + (size_t)262144 * ((widx << 2) | batch);
  const int bnl = (blockIdx.y & 3) << 7;
  const int wr = (wave >> 1) << 6;
  const int wc = (wave & 1) << 6;
  const int lr = lane & 15, lg = lane >> 4;

  f32x4 acc[4][4] = {};
  const int srow = lane >> 3;
  const int sslot = (lane & 7) ^ srow;

  for (int k0 = 0; k0 < 512; k0 += 64) {
    __syncthreads();
#pragma unroll
    for (int i = 0; i < 4; ++i) {
      const int ci = wave * 4 + i;
      const int row = ci * 8 + srow;
      GLOAD16(A + (size_t)(bm + row) * 512 + k0 + sslot * 8, (char*)As + ci * 1024);
      GLOAD16(B + (size_t)(bnl + row) * 512 + k0 + sslot * 8, (char*)Bs + ci * 1024);
    }
    __syncthreads();
#pragma unroll
    for (int kk = 0; kk < 64; kk += 32) {
      bf16x8 af[4], bfr[4];
#pragma unroll
      for (int i = 0; i < 4; ++i) {
        const int row = wr + i * 16 + lr;
        af[i] = *(const bf16x8*)&As[row * 64 + ((((kk >> 3) + lg) ^ (row & 7)) << 3)];
      }
#pragma unroll
      for (int j = 0; j < 4; ++j) {
        const int row = wc + j * 16 + lr;
        bfr[j] = *(const bf16x8*)&Bs[row * 64 + ((((kk >> 3) + lg) ^ (row & 7)) << 3)];
      }
#pragma unroll
      for (int i = 0; i < 4; ++i)
#pragma unroll
        for (int j = 0; j < 4; ++j)
          acc[i][j] = __builtin_amdgcn_mfma_f32_16x16x32_bf16(af[i], bfr[j], acc[i][j], 0, 0, 0);
    }
  }

  {
    const float* cb = corr + (((widx << 2) | batch) << 9);
    float cj[4];
#pragma unroll
    for (int j = 0; j < 4; ++j) cj[j] = cb[bnl + wc + j * 16 + lr];
#pragma unroll
    for (int i = 0; i < 4; ++i)
#pragma unroll
      for (int j = 0; j < 4; ++j)
#pragma unroll
        for (int r = 0; r < 4; ++r) acc[i][j][r] -= cj[j];
  }

  if (first) {
    unsigned short* C0 = z ? k16 : q16;
#pragma unroll
    for (int i = 0; i < 4; ++i) {
      const int row0 = bm + wr + i * 16 + lg * 4;
#pragma unroll
      for (int j = 0; j < 4; ++j) {
        const int col = bnl + wc + j * 16 + lr;
#pragma unroll
        for (int r = 0; r < 4; ++r)
          C0[(size_t)(row0 + r) * 512 + col] = f2b(acc[i][j][r]);
      }
    }
    float s = 0.f, sq = 0.f;
#pragma unroll
    for (int i = 0; i < 4; ++i)
#pragma unroll
      for (int j = 0; j < 4; ++j)
#pragma unroll
        for (int r = 0; r < 4; ++r) { const float v = acc[i][j][r]; s += v; sq += v * v; }
#pragma unroll
    for (int o = 32; o > 0; o >>= 1) { s += __shfl_xor(s, o); sq += __shfl_xor(sq, o); }
    if (lane == 0) { red[wave * 2] = s; red[wave * 2 + 1] = sq; }
    __syncthreads();
    if (tid == 0) {
      float* part = z ? part_k : part_q;
      const float S = red[0] + red[2] + red[4] + red[6];
      const float SQ = red[1] + red[3] + red[5] + red[7];
      const int slot = blockIdx.x & 31, g = blockIdx.y;
      const int idx = ((((batch << 2) | g) << 5) | slot) << 1;
      part[idx] = S;
      part[idx + 1] = SQ;
    }
    if (z) {
      const int head = (bnl >> 6) + (wave & 1);
#pragma unroll
      for (int i = 0; i < 4; ++i) {
#pragma unroll
        for (int r = 0; r < 4; ++r) {
          float t = acc[i][0][r] + acc[i][1][r] + acc[i][2][r] + acc[i][3][r];
#pragma unroll
          for (int o = 1; o < 16; o <<= 1) t += __shfl_xor(t, o);
          if (lr == 0)
            sk[(size_t)(bm + wr + i * 16 + lg * 4 + r) * 8 + head] = t;
        }
      }
    }
  } else if (z == 0) {
#pragma unroll
    for (int i = 0; i < 4; ++i) {
      const int row0 = bm + wr + i * 16 + lg * 4;
#pragma unroll
      for (int j = 0; j < 4; ++j) {
        const int col = bnl + wc + j * 16 + lr;
        const float bb = b1[col];
#pragma unroll
        for (int r = 0; r < 4; ++r) {
          float v = acc[i][j][r] + bb;
          v = v > 0.f ? v : 0.01f * v;
          h16[(size_t)(row0 + r) * 512 + col] = f2b(v);
        }
      }
    }
  } else {
#pragma unroll
    for (int i = 0; i < 4; ++i) {
      const int row0 = bm + wr + i * 16 + lg * 4;
#pragma unroll
      for (int j = 0; j < 4; ++j) {
        const int col = bnl + wc + j * 16 + lr;
        us4 pk;
#pragma unroll
        for (int r = 0; r < 4; ++r) pk[r] = f2b(acc[i][j][r]);
        *(us4*)&vTb[((size_t)(row0 >> 9) * 512 + col) * 512 + (row0 & 511)] = pk;
      }
    }
  }
}

// ---------------- final GEMM: out = [ao|h1](K=1024) @ [Wz|W2]^T + bz+b2 + in_f(bf16) -------
__global__ __launch_bounds__(256) void gemm_final(const unsigned short* __restrict__ A0,
                                                  const unsigned short* __restrict__ A1,
                                                  const unsigned short* __restrict__ B0,
                                                  const unsigned short* __restrict__ B1,
                                                  float* __restrict__ Cf,
                                                  const float* __restrict__ bias0,
                                                  const float* __restrict__ bias1,
                                                  const unsigned short* __restrict__ init16) {
  __shared__ __align__(16) unsigned short As[128 * 64];
  __shared__ __align__(16) unsigned short Bs[128 * 64];
  const int tid = threadIdx.x;
  const int wave = tid >> 6, lane = tid & 63;
  const int bm = blockIdx.x << 7, bn = blockIdx.y << 7;
  const int wr = (wave >> 1) << 6;
  const int wc = (wave & 1) << 6;
  const int lr = lane & 15, lg = lane >> 4;

  f32x4 acc[4][4] = {};
  const int srow = lane >> 3;
  const int sslot = (lane & 7) ^ srow;

  for (int k0 = 0; k0 < 1024; k0 += 64) {
    const unsigned short* Ab = (k0 < 512) ? A0 : A1;
    const unsigned short* Bb = (k0 < 512) ? B0 : B1;
    const int kl = k0 & 511;
    __syncthreads();
#pragma unroll
    for (int i = 0; i < 4; ++i) {
      const int ci = wave * 4 + i;
      const int row = ci * 8 + srow;
      GLOAD16(Ab + (size_t)(bm + row) * 512 + kl + sslot * 8, (char*)As + ci * 1024);
      GLOAD16(Bb + (size_t)(bn + row) * 512 + kl + sslot * 8, (char*)Bs + ci * 1024);
    }
    __syncthreads();
#pragma unroll
    for (int kk = 0; kk < 64; kk += 32) {
      bf16x8 af[4], bfr[4];
#pragma unroll
      for (int i = 0; i < 4; ++i) {
        const int row = wr + i * 16 + lr;
        af[i] = *(const bf16x8*)&As[row * 64 + ((((kk >> 3) + lg) ^ (row & 7)) << 3)];
      }
#pragma unroll
      for (int j = 0; j < 4; ++j) {
        const int row = wc + j * 16 + lr;
        bfr[j] = *(const bf16x8*)&Bs[row * 64 + ((((kk >> 3) + lg) ^ (row & 7)) << 3)];
      }
#pragma unroll
      for (int i = 0; i < 4; ++i)
#pragma unroll
        for (int j = 0; j < 4; ++j)
          acc[i][j] = __builtin_amdgcn_mfma_f32_16x16x32_bf16(af[i], bfr[j], acc[i][j], 0, 0, 0);
    }
  }

#pragma unroll
  for (int i = 0; i < 4; ++i) {
    const int row0 = bm + wr + i * 16 + lg * 4;
#pragma unroll
    for (int j = 0; j < 4; ++j) {
      const int col = bn + wc + j * 16 + lr;
      const float bb = bias0[col] + bias1[col];
#pragma unroll
      for (int r = 0; r < 4; ++r) {
        const size_t o = (size_t)(row0 + r) * 512 + col;
        Cf[o] = acc[i][j][r] + bb + b2f(init16[o]);
      }
    }
  }
}

// ------- fused attention (R8 structure): GN folded; V-half0 prefetch; plain P stores -------
__global__ __launch_bounds__(256) void attn_fused(const unsigned short* __restrict__ q16,
                                                  const unsigned short* __restrict__ k16,
                                                  const unsigned short* __restrict__ vT,
                                                  const float* __restrict__ part_q,
                                                  const float* __restrict__ part_k,
                                                  const float* __restrict__ sk,
                                                  float* __restrict__ aw,
                                                  unsigned short* __restrict__ ao16) {
  __shared__ __align__(16) unsigned short Qs[64 * 64];
  __shared__ __align__(16) unsigned short Ks[256 * 64];
  __shared__ __align__(16) unsigned short Ps[64 * 256];
  __shared__ float WM[4][64];
  __shared__ float WS[4][64];
  __shared__ float sk_lds[512];
  __shared__ float cst[2];

  const int bid = blockIdx.x;
  const int q0 = blockIdx.y << 6;
  const int h = bid & 7;
  const int b = bid >> 6;
  const int tid = threadIdx.x;
  const int w = tid >> 6, lane = tid & 63;
  const int lr = lane & 15, lg = lane >> 4;
  const int srow = lane >> 3;
  const int sslot = (lane & 7) ^ srow;

  const size_t hb = (size_t)(bid >> 3) * (512 * 512);
  const unsigned short* Qg = q16 + hb + h * 64;
  const unsigned short* Kg = k16 + hb + h * 64;
  const unsigned short* Vg = vT + hb + (size_t)h * 64 * 512;

  if (tid == 0) {
    const int pbase = (((b << 2) | (h >> 1)) << 6);
    const float* pq = part_q + pbase;
    const float* pk = part_k + pbase;
    float Sq = 0.f, SQq = 0.f, Sk = 0.f, SQk = 0.f;
    for (int c = 0; c < 32; ++c) {
      Sq += pq[c * 2]; SQq += pq[c * 2 + 1];
      Sk += pk[c * 2]; SQk += pk[c * 2 + 1];
    }
    const float inv = 1.f / (float)(NTROWS * 128);
    const float muq = Sq * inv, vq = SQq * inv - muq * muq;
    const float muk = Sk * inv, vk = SQk * inv - muk * muk;
    const float a = rsqrtf(vq + EPSGN) * rsqrtf(vk + EPSGN) * 0.125f;
    cst[0] = a;
    cst[1] = a * muq;
  }
  {
    const float* skg = sk + (size_t)(bid >> 3) * 512 * 8 + h;
    for (int j = tid; j < 512; j += 256) sk_lds[j] = skg[(size_t)j * 8];
  }

#pragma unroll
  for (int it = 0; it < 2; ++it) {  // stage Q 64x64 async
    const int ci = w * 2 + it;
    const int row = ci * 8 + srow;
    GLOAD16(Qg + (size_t)(q0 + row) * 512 + sslot * 8, (char*)Qs + ci * 1024);
  }

  f32x4 sc[4][8] = {};

#pragma unroll
  for (int half = 0; half < 2; ++half) {
    __syncthreads();
#pragma unroll
    for (int it = 0; it < 8; ++it) {  // stage K half (per-wave region) async
      const int ci = w * 8 + it;
      const int row = ci * 8 + srow;
      GLOAD16(Kg + (size_t)(half * 256 + row) * 512 + sslot * 8, (char*)Ks + ci * 1024);
    }
    __syncthreads();
#pragma unroll
    for (int kk = 0; kk < 64; kk += 32) {
      bf16x8 aq[4];
#pragma unroll
      for (int qf = 0; qf < 4; ++qf) {
        const int row = qf * 16 + lr;
        aq[qf] = *(const bf16x8*)&Qs[row * 64 + ((((kk >> 3) + lg) ^ (row & 7)) << 3)];
      }
#pragma unroll
      for (int kf = 0; kf < 4; ++kf) {
        const int row = w * 64 + kf * 16 + lr;
        const bf16x8 bk = *(const bf16x8*)&Ks[row * 64 + ((((kk >> 3) + lg) ^ (row & 7)) << 3)];
#pragma unroll
        for (int qf = 0; qf < 4; ++qf)
          sc[qf][half * 4 + kf] =
              __builtin_amdgcn_mfma_f32_16x16x32_bf16(aq[qf], bk, sc[qf][half * 4 + kf], 0, 0, 0);
      }
    }
  }

  // issue V half0 into this wave's own Ks region (QK ds_reads complete; no cross-wave reads)
#pragma unroll
  for (int it = 0; it < 8; ++it) {
    const int ci = w * 8 + it;
    const int row = ci * 2 + (lane >> 5);
    const int s = lane & 31;
    GLOAD16(Vg + (size_t)row * 512 + ((s ^ (row & 7)) << 3), (char*)Ks + ci * 1024);
  }

  // ---- GN correction: logit = a*S - a*mu_q*Sk[col] ----
  const float aSc = cst[0], cmu = cst[1];
#pragma unroll
  for (int qf = 0; qf < 4; ++qf)
#pragma unroll
    for (int kfi = 0; kfi < 8; ++kfi) {
      const int k = ((kfi >> 2) << 8) + w * 64 + ((kfi & 3) << 4) + lr;
      const float corr = cmu * sk_lds[k];
#pragma unroll
      for (int r = 0; r < 4; ++r) sc[qf][kfi][r] = aSc * sc[qf][kfi][r] - corr;
    }

  // ---- softmax ----
  float Mv[4][4];
#pragma unroll
  for (int qf = 0; qf < 4; ++qf)
#pragma unroll
    for (int r = 0; r < 4; ++r) {
      float m = sc[qf][0][r];
#pragma unroll
      for (int kf = 1; kf < 8; ++kf) m = fmaxf(m, sc[qf][kf][r]);
#pragma unroll
      for (int o = 1; o < 16; o <<= 1) m = fmaxf(m, __shfl_xor(m, o));
      Mv[qf][r] = m;
    }
  if (lr == 0) {
#pragma unroll
    for (int qf = 0; qf < 4; ++qf)
#pragma unroll
      for (int r = 0; r < 4; ++r) WM[w][qf * 16 + lg * 4 + r] = Mv[qf][r];
  }
  __syncthreads();
#pragma unroll
  for (int qf = 0; qf < 4; ++qf)
#pragma unroll
    for (int r = 0; r < 4; ++r) {
      const int q = qf * 16 + lg * 4 + r;
      Mv[qf][r] = fmaxf(fmaxf(WM[0][q], WM[1][q]), fmaxf(WM[2][q], WM[3][q]));
    }
  float sl[4][4] = {};
#pragma unroll
  for (int qf = 0; qf < 4; ++qf)
#pragma unroll
    for (int kf = 0; kf < 8; ++kf) {
      f32x4 v = sc[qf][kf];
#pragma unroll
      for (int r = 0; r < 4; ++r) {
        const float e = __expf(v[r] - Mv[qf][r]);
        v[r] = e;
        sl[qf][r] += e;
      }
      sc[qf][kf] = v;
    }
#pragma unroll
  for (int qf = 0; qf < 4; ++qf)
#pragma unroll
    for (int r = 0; r < 4; ++r) {
      float s = sl[qf][r];
#pragma unroll
      for (int o = 1; o < 16; o <<= 1) s += __shfl_xor(s, o);
      sl[qf][r] = s;
    }
  if (lr == 0) {
#pragma unroll
    for (int qf = 0; qf < 4; ++qf)
#pragma unroll
      for (int r = 0; r < 4; ++r) WS[w][qf * 16 + lg * 4 + r] = sl[qf][r];
  }
  __syncthreads();
#pragma unroll
  for (int qf = 0; qf < 4; ++qf)
#pragma unroll
    for (int r = 0; r < 4; ++r) {
      const int q = qf * 16 + lg * 4 + r;
      const float inv = 1.f / (WS[0][q] + WS[1][q] + WS[2][q] + WS[3][q]);
#pragma unroll
      for (int kf = 0; kf < 8; ++kf) sc[qf][kf][r] *= inv;
    }

  // ---- write P (fp32, PLAIN stores: let L2 coalesce adjacent 64B segments) ----
  float* AWp = aw + ((size_t)bid * 512 + q0) * 512;
#pragma unroll
  for (int qf = 0; qf < 4; ++qf)
#pragma unroll
    for (int kfi = 0; kfi < 8; ++kfi) {
      const int k = ((kfi >> 2) << 8) + w * 64 + ((kfi & 3) << 4) + lr;
#pragma unroll
      for (int r = 0; r < 4; ++r)
        AWp[(size_t)(qf * 16 + lg * 4 + r) * 512 + k] = sc[qf][kfi][r];
    }

  // ---- stage P half0 (bf16) swizzled ----
#pragma unroll
  for (int qf = 0; qf < 4; ++qf)
#pragma unroll
    for (int r = 0; r < 4; ++r) {
      const int q = qf * 16 + lg * 4 + r;
#pragma unroll
      for (int kf = 0; kf < 4; ++kf) {
        const int k = w * 64 + (kf << 4) + lr;
        Ps[q * 256 + (((k >> 3) ^ (q & 7)) << 3) + (k & 7)] = f2b(sc[qf][kf][r]);
      }
    }
  __syncthreads();  // V0 (vmcnt) + Ps0 (lgkm) complete for all waves

  f32x4 accO[4] = {};
#pragma unroll
  for (int ks = 0; ks < 256; ks += 32) {
    const int sl0 = ks >> 3;
    const int q = w * 16 + lr;
    const bf16x8 af = *(const bf16x8*)&Ps[q * 256 + (((sl0 + lg) ^ (q & 7)) << 3)];
#pragma unroll
    for (int df = 0; df < 4; ++df) {
      const int row = df * 16 + lr;
      const bf16x8 vb = *(const bf16x8*)&Ks[row * 256 + (((sl0 + lg) ^ (row & 7)) << 3)];
      accO[df] = __builtin_amdgcn_mfma_f32_16x16x32_bf16(af, vb, accO[df], 0, 0, 0);
    }
  }
  __syncthreads();  // all waves done reading V0/Ps0

  // issue V half1 + stage P half1
#pragma unroll
  for (int it = 0; it < 8; ++it) {
    const int ci = w * 8 + it;
    const int row = ci * 2 + (lane >> 5);
    const int s = lane & 31;
    GLOAD16(Vg + (size_t)row * 512 + 256 + ((s ^ (row & 7)) << 3), (char*)Ks + ci * 1024);
  }
#pragma unroll
  for (int qf = 0; qf < 4; ++qf)
#pragma unroll
    for (int r = 0; r < 4; ++r) {
      const int q = qf * 16 + lg * 4 + r;
#pragma unroll
      for (int kf = 0; kf < 4; ++kf) {
        const int k = w * 64 + (kf << 4) + lr;
        Ps[q * 256 + (((k >> 3) ^ (q & 7)) << 3) + (k & 7)] = f2b(sc[qf][4 + kf][r]);
      }
    }
  __syncthreads();

#pragma unroll
  for (int ks = 0; ks < 256; ks += 32) {
    const int sl0 = ks >> 3;
    const int q = w * 16 + lr;
    const bf16x8 af = *(const bf16x8*)&Ps[q * 256 + (((sl0 + lg) ^ (q & 7)) << 3)];
#pragma unroll
    for (int df = 0; df < 4; ++df) {
      const int row = df * 16 + lr;
      const bf16x8 vb = *(const bf16x8*)&Ks[row * 256 + (((sl0 + lg) ^ (row & 7)) << 3)];
      accO[df] = __builtin_amdgcn_mfma_f32_16x16x32_bf16(af, vb, accO[df], 0, 0, 0);
    }
  }

  const int growb = (bid >> 3) * 512 + q0 + w * 16 + lg * 4;
#pragma unroll
  for (int df = 0; df < 4; ++df)
#pragma unroll
    for (int r = 0; r < 4; ++r)
      ao16[(size_t)(growb + r) * 512 + h * 64 + df * 16 + lr] = f2b(accO[df][r]);
}

// ---------------- launcher ----------------
extern "C" void kernel_launch(void* const* d_in, const int* in_sizes, int n_in,
                              void* d_out, int out_size, void* d_ws, size_t ws_size,
                              hipStream_t stream) {
  const float* in_f = (const float*)d_in[1];
  const float* in_fkv = (const float*)d_in[2];
  const float* Wq = (const float*)d_in[3];
  const float* Wk = (const float*)d_in[4];
  const float* Wv = (const float*)d_in[5];
  const float* Wz = (const float*)d_in[6];
  const float* bz = (const float*)d_in[7];
  const float* W1 = (const float*)d_in[8];
  const float* b1 = (const float*)d_in[9];
  const float* W2 = (const float*)d_in[10];
  const float* b2 = (const float*)d_in[11];

  float* out_f = (float*)d_out;
  float* attw = out_f + (size_t)MROWS * DDIM;

  const size_t TSB = (size_t)MROWS * DDIM;
  unsigned short* us = (unsigned short*)d_ws;
  unsigned short* a16 = us;
  unsigned short* akv16 = us + TSB;
  unsigned short* q16 = us + 2 * TSB;
  unsigned short* k16 = us + 3 * TSB;
  unsigned short* h16 = us + 4 * TSB;
  unsigned short* ao16 = us + 5 * TSB;
  unsigned short* vT = us + 6 * TSB;
  unsigned short* w16s = us + 7 * TSB;
  float* fbase = (float*)(us + 7 * TSB + 18 * 262144);
  float* p0 = fbase;
  float* p1 = fbase + 4096;
  float* part_q = fbase + 8192;
  float* part_k = fbase + 9216;
  float* corr = fbase + 10240;
  float* sk = fbase + 18432;

  stats_cvt<<<dim3(512, 3), 256, 0, stream>>>(in_f, in_fkv, a16, akv16, p0, p1, Wz, W2, w16s);
  wprep<<<dim3(128, 16), 256, 0, stream>>>(Wq, Wk, Wv, W1, p0, p1, w16s, corr);
  gemm_all<<<dim3(128, 8, 2), 256, 0, stream>>>(a16, akv16, w16s, corr, q16, h16, k16, vT, b1,
                                                part_q, part_k, sk);
  attn_fused<<<dim3(256, 8), 256, 0, stream>>>(q16, k16, vT, part_q, part_k, sk, attw, ao16);
  gemm_final<<<dim3(128, 4), 256, 0, stream>>>(ao16, h16, w16s + 16 * 262144,
                                               w16s + 17 * 262144, out_f, bz, b2, a16);
}

// Round 11
// 238.236 us; speedup vs baseline: 1.1713x; 1.1219x over previous
//
#include <hip/hip_runtime.h>
#include <math.h>

#define TDIM 512
#define DDIM 512
#define NTROWS 4096
#define MROWS 16384
#define EPSGN 1e-3f

typedef __attribute__((ext_vector_type(8))) short bf16x8;
typedef __attribute__((ext_vector_type(4))) float f32x4;
typedef __attribute__((ext_vector_type(8))) unsigned short us8;
typedef __attribute__((ext_vector_type(4))) unsigned short us4;

__device__ __forceinline__ unsigned short f2b(float f) {
  unsigned int u = __float_as_uint(f);
  return (unsigned short)((u + 0x7fffu + ((u >> 16) & 1u)) >> 16);
}
__device__ __forceinline__ float b2f(unsigned short h) {
  return __uint_as_float(((unsigned int)h) << 16);
}

#define GLOAD16(g, l)                                                                   \
  __builtin_amdgcn_global_load_lds((const __attribute__((address_space(1))) void*)(g),  \
                                   (__attribute__((address_space(3))) void*)(l), 16, 0, 0)

// ------- fused: fp32 -> raw bf16 convert + GroupNorm partial stats (+ Wz/W2 convert) -------
__global__ __launch_bounds__(256) void stats_cvt(const float* __restrict__ x0,
                                                 const float* __restrict__ x1,
                                                 unsigned short* __restrict__ o0,
                                                 unsigned short* __restrict__ o1,
                                                 float* __restrict__ p0,
                                                 float* __restrict__ p1,
                                                 const float* __restrict__ Wz,
                                                 const float* __restrict__ W2,
                                                 unsigned short* __restrict__ w16s) {
  if (blockIdx.y == 2) {
    const int bid = blockIdx.x;
    if (bid >= 256) return;
    const int c = bid * 256 + threadIdx.x;
    const int t = c >> 15;
    const int off = c & 32767;
    const float* s = t ? W2 : Wz;
    unsigned short* d = w16s + (size_t)(16 + t) * 262144;
    const float4 f0 = *(const float4*)(s + (size_t)off * 8);
    const float4 f1 = *(const float4*)(s + (size_t)off * 8 + 4);
    us8 v;
    v[0] = f2b(f0.x); v[1] = f2b(f0.y); v[2] = f2b(f0.z); v[3] = f2b(f0.w);
    v[4] = f2b(f1.x); v[5] = f2b(f1.y); v[6] = f2b(f1.z); v[7] = f2b(f1.w);
    *(us8*)(d + (size_t)off * 8) = v;
    return;
  }
  const float* x = blockIdx.y ? x1 : x0;
  unsigned short* o = blockIdx.y ? o1 : o0;
  float* part = blockIdx.y ? p1 : p0;
  const int blk = blockIdx.x;
  const int batch = blk >> 7;
  const int chunk = blk & 127;
  const size_t base = (size_t)blk * 32 * 512;
  const int tid = threadIdx.x;
  float s = 0.f, sq = 0.f;
#pragma unroll 4
  for (int it = 0; it < 8; ++it) {
    const size_t e = base + (size_t)it * 2048 + (size_t)tid * 8;
    const float4 f0 = *(const float4*)(x + e);
    const float4 f1 = *(const float4*)(x + e + 4);
    us8 v;
    v[0] = f2b(f0.x); v[1] = f2b(f0.y); v[2] = f2b(f0.z); v[3] = f2b(f0.w);
    v[4] = f2b(f1.x); v[5] = f2b(f1.y); v[6] = f2b(f1.z); v[7] = f2b(f1.w);
    *(us8*)(o + e) = v;
    s += f0.x + f0.y + f0.z + f0.w + f1.x + f1.y + f1.z + f1.w;
    sq += f0.x * f0.x + f0.y * f0.y + f0.z * f0.z + f0.w * f0.w +
          f1.x * f1.x + f1.y * f1.y + f1.z * f1.z + f1.w * f1.w;
  }
  const int wave = tid >> 6, lane = tid & 63;
#pragma unroll
  for (int of = 1; of < 16; of <<= 1) { s += __shfl_xor(s, of); sq += __shfl_xor(sq, of); }
  __shared__ float red[4][4][2];
  if ((lane & 15) == 0) { red[wave][lane >> 4][0] = s; red[wave][lane >> 4][1] = sq; }
  __syncthreads();
  if (tid < 4) {
    float S = 0.f, SQ = 0.f;
#pragma unroll
    for (int w = 0; w < 4; ++w) { S += red[w][tid][0]; SQ += red[w][tid][1]; }
    const int idx = (((batch << 2) | tid) << 7) | chunk;
    part[idx * 2] = S;
    part[idx * 2 + 1] = SQ;
  }
}

// ---------------- weight prep: per-batch GN-scaled weights + column corrections ------------
__global__ __launch_bounds__(256) void wprep(const float* __restrict__ Wq,
                                             const float* __restrict__ Wk,
                                             const float* __restrict__ Wv,
                                             const float* __restrict__ W1,
                                             const float* __restrict__ p0,
                                             const float* __restrict__ p1,
                                             unsigned short* __restrict__ w16s,
                                             float* __restrict__ corr) {
  const int y = blockIdx.y;
  const int w = y >> 2, b = y & 3;
  const float* W = (w == 0) ? Wq : (w == 1) ? Wk : (w == 2) ? Wv : W1;
  const float* part = (w == 0 || w == 3) ? p0 : p1;
  __shared__ float mrs[4][2];
  if (threadIdx.x < 4) {
    const float* p = part + (((b << 2) | threadIdx.x) << 7) * 2;
    float S = 0.f, SQ = 0.f;
    for (int c = 0; c < 128; ++c) { S += p[c * 2]; SQ += p[c * 2 + 1]; }
    const float inv = 1.f / (float)(NTROWS * 128);
    const float mu = S * inv;
    const float var = SQ * inv - mu * mu;
    const float rs = rsqrtf(var + EPSGN);
    mrs[threadIdx.x][0] = rs;
    mrs[threadIdx.x][1] = mu * rs;
  }
  __syncthreads();
  const int wave = threadIdx.x >> 6, lane = threadIdx.x & 63;
  const int n = blockIdx.x * 4 + wave;
  const int k = lane * 8;
  const int g = lane >> 4;
  const float rs = mrs[g][0], murs = mrs[g][1];
  const float4 f0 = *(const float4*)(W + (size_t)n * 512 + k);
  const float4 f1 = *(const float4*)(W + (size_t)n * 512 + k + 4);
  us8 v;
  v[0] = f2b(f0.x * rs); v[1] = f2b(f0.y * rs); v[2] = f2b(f0.z * rs); v[3] = f2b(f0.w * rs);
  v[4] = f2b(f1.x * rs); v[5] = f2b(f1.y * rs); v[6] = f2b(f1.z * rs); v[7] = f2b(f1.w * rs);
  *(us8*)(w16s + (size_t)((w << 2) | b) * 262144 + (size_t)n * 512 + k) = v;
  float t = (f0.x + f0.y + f0.z + f0.w + f1.x + f1.y + f1.z + f1.w) * murs;
#pragma unroll
  for (int of = 1; of < 64; of <<= 1) t += __shfl_xor(t, of);
  if (lane == 0) corr[(((w << 2) | b) << 9) | n] = t;
}

// ---------------- unified projection GEMMs (grid (128,8,2), XCD-swizzled) ----------------
// XCD remap: physical p -> (bx = (p&7)*16 + (m&15), y = (m>>4)&7, z = m>>7), m = p>>3.
// Each XCD owns a contiguous 16-wide bx band -> A row-panels fetched once per XCD (L2-fit).
__global__ __launch_bounds__(256) void gemm_all(const unsigned short* __restrict__ a16,
                                                const unsigned short* __restrict__ akv16,
                                                const unsigned short* __restrict__ w16s,
                                                const float* __restrict__ corr,
                                                unsigned short* __restrict__ q16,
                                                unsigned short* __restrict__ h16,
                                                unsigned short* __restrict__ k16,
                                                unsigned short* __restrict__ vTb,
                                                const float* __restrict__ b1,
                                                float* __restrict__ part_q,
                                                float* __restrict__ part_k,
                                                float* __restrict__ sk) {
  __shared__ __align__(16) unsigned short As[128 * 64];
  __shared__ __align__(16) unsigned short Bs[128 * 64];
  __shared__ float red[8];
  const int p = blockIdx.x + (blockIdx.y << 7) + (blockIdx.z << 10);
  const int xc = p & 7, m = p >> 3;
  const int bxi = (xc << 4) | (m & 15);
  const int yi = (m >> 4) & 7;
  const int z = m >> 7;
  const int tid = threadIdx.x;
  const int wave = tid >> 6, lane = tid & 63;
  const int bm = bxi << 7;
  const int batch = bxi >> 5;
  const bool first = yi < 4;
  const int widx = z ? (first ? 1 : 2) : (first ? 0 : 3);
  const unsigned short* A = z ? akv16 : a16;
  const unsigned short* B = w16s + (size_t)262144 * ((widx << 2) | batch);
  const int bnl = (yi & 3) << 7;
  const int wr = (wave >> 1) << 6;
  const int wc = (wave & 1) << 6;
  const int lr = lane & 15, lg = lane >> 4;

  f32x4 acc[4][4] = {};
  const int srow = lane >> 3;
  const int sslot = (lane & 7) ^ srow;

  for (int k0 = 0; k0 < 512; k0 += 64) {
    __syncthreads();
#pragma unroll
    for (int i = 0; i < 4; ++i) {
      const int ci = wave * 4 + i;
      const int row = ci * 8 + srow;
      GLOAD16(A + (size_t)(bm + row) * 512 + k0 + sslot * 8, (char*)As + ci * 1024);
      GLOAD16(B + (size_t)(bnl + row) * 512 + k0 + sslot * 8, (char*)Bs + ci * 1024);
    }
    __syncthreads();
#pragma unroll
    for (int kk = 0; kk < 64; kk += 32) {
      bf16x8 af[4], bfr[4];
#pragma unroll
      for (int i = 0; i < 4; ++i) {
        const int row = wr + i * 16 + lr;
        af[i] = *(const bf16x8*)&As[row * 64 + ((((kk >> 3) + lg) ^ (row & 7)) << 3)];
      }
#pragma unroll
      for (int j = 0; j < 4; ++j) {
        const int row = wc + j * 16 + lr;
        bfr[j] = *(const bf16x8*)&Bs[row * 64 + ((((kk >> 3) + lg) ^ (row & 7)) << 3)];
      }
#pragma unroll
      for (int i = 0; i < 4; ++i)
#pragma unroll
        for (int j = 0; j < 4; ++j)
          acc[i][j] = __builtin_amdgcn_mfma_f32_16x16x32_bf16(af[i], bfr[j], acc[i][j], 0, 0, 0);
    }
  }

  {
    const float* cb = corr + (((widx << 2) | batch) << 9);
    float cj[4];
#pragma unroll
    for (int j = 0; j < 4; ++j) cj[j] = cb[bnl + wc + j * 16 + lr];
#pragma unroll
    for (int i = 0; i < 4; ++i)
#pragma unroll
      for (int j = 0; j < 4; ++j)
#pragma unroll
        for (int r = 0; r < 4; ++r) acc[i][j][r] -= cj[j];
  }

  if (first) {
    unsigned short* C0 = z ? k16 : q16;
#pragma unroll
    for (int i = 0; i < 4; ++i) {
      const int row0 = bm + wr + i * 16 + lg * 4;
#pragma unroll
      for (int j = 0; j < 4; ++j) {
        const int col = bnl + wc + j * 16 + lr;
#pragma unroll
        for (int r = 0; r < 4; ++r)
          C0[(size_t)(row0 + r) * 512 + col] = f2b(acc[i][j][r]);
      }
    }
    float s = 0.f, sq = 0.f;
#pragma unroll
    for (int i = 0; i < 4; ++i)
#pragma unroll
      for (int j = 0; j < 4; ++j)
#pragma unroll
        for (int r = 0; r < 4; ++r) { const float v = acc[i][j][r]; s += v; sq += v * v; }
#pragma unroll
    for (int o = 32; o > 0; o >>= 1) { s += __shfl_xor(s, o); sq += __shfl_xor(sq, o); }
    if (lane == 0) { red[wave * 2] = s; red[wave * 2 + 1] = sq; }
    __syncthreads();
    if (tid == 0) {
      float* part = z ? part_k : part_q;
      const float S = red[0] + red[2] + red[4] + red[6];
      const float SQ = red[1] + red[3] + red[5] + red[7];
      const int slot = bxi & 31, g = yi;
      const int idx = ((((batch << 2) | g) << 5) | slot) << 1;
      part[idx] = S;
      part[idx + 1] = SQ;
    }
    if (z) {
      const int head = (bnl >> 6) + (wave & 1);
#pragma unroll
      for (int i = 0; i < 4; ++i) {
#pragma unroll
        for (int r = 0; r < 4; ++r) {
          float t = acc[i][0][r] + acc[i][1][r] + acc[i][2][r] + acc[i][3][r];
#pragma unroll
          for (int o = 1; o < 16; o <<= 1) t += __shfl_xor(t, o);
          if (lr == 0)
            sk[(size_t)(bm + wr + i * 16 + lg * 4 + r) * 8 + head] = t;
        }
      }
    }
  } else if (z == 0) {
#pragma unroll
    for (int i = 0; i < 4; ++i) {
      const int row0 = bm + wr + i * 16 + lg * 4;
#pragma unroll
      for (int j = 0; j < 4; ++j) {
        const int col = bnl + wc + j * 16 + lr;
        const float bb = b1[col];
#pragma unroll
        for (int r = 0; r < 4; ++r) {
          float v = acc[i][j][r] + bb;
          v = v > 0.f ? v : 0.01f * v;
          h16[(size_t)(row0 + r) * 512 + col] = f2b(v);
        }
      }
    }
  } else {
#pragma unroll
    for (int i = 0; i < 4; ++i) {
      const int row0 = bm + wr + i * 16 + lg * 4;
#pragma unroll
      for (int j = 0; j < 4; ++j) {
        const int col = bnl + wc + j * 16 + lr;
        us4 pk;
#pragma unroll
        for (int r = 0; r < 4; ++r) pk[r] = f2b(acc[i][j][r]);
        *(us4*)&vTb[((size_t)(row0 >> 9) * 512 + col) * 512 + (row0 & 511)] = pk;
      }
    }
  }
}

// -------- final GEMM (grid (128,4), XCD-swizzled): out = [ao|h1] @ [Wz|W2]^T + ... --------
__global__ __launch_bounds__(256) void gemm_final(const unsigned short* __restrict__ A0,
                                                  const unsigned short* __restrict__ A1,
                                                  const unsigned short* __restrict__ B0,
                                                  const unsigned short* __restrict__ B1,
                                                  float* __restrict__ Cf,
                                                  const float* __restrict__ bias0,
                                                  const float* __restrict__ bias1,
                                                  const unsigned short* __restrict__ init16) {
  __shared__ __align__(16) unsigned short As[128 * 64];
  __shared__ __align__(16) unsigned short Bs[128 * 64];
  const int p = blockIdx.x + (blockIdx.y << 7);
  const int xc = p & 7, m = p >> 3;
  const int bxi = (xc << 4) | (m & 15);
  const int bni = (m >> 4) & 3;
  const int tid = threadIdx.x;
  const int wave = tid >> 6, lane = tid & 63;
  const int bm = bxi << 7, bn = bni << 7;
  const int wr = (wave >> 1) << 6;
  const int wc = (wave & 1) << 6;
  const int lr = lane & 15, lg = lane >> 4;

  f32x4 acc[4][4] = {};
  const int srow = lane >> 3;
  const int sslot = (lane & 7) ^ srow;

  for (int k0 = 0; k0 < 1024; k0 += 64) {
    const unsigned short* Ab = (k0 < 512) ? A0 : A1;
    const unsigned short* Bb = (k0 < 512) ? B0 : B1;
    const int kl = k0 & 511;
    __syncthreads();
#pragma unroll
    for (int i = 0; i < 4; ++i) {
      const int ci = wave * 4 + i;
      const int row = ci * 8 + srow;
      GLOAD16(Ab + (size_t)(bm + row) * 512 + kl + sslot * 8, (char*)As + ci * 1024);
      GLOAD16(Bb + (size_t)(bn + row) * 512 + kl + sslot * 8, (char*)Bs + ci * 1024);
    }
    __syncthreads();
#pragma unroll
    for (int kk = 0; kk < 64; kk += 32) {
      bf16x8 af[4], bfr[4];
#pragma unroll
      for (int i = 0; i < 4; ++i) {
        const int row = wr + i * 16 + lr;
        af[i] = *(const bf16x8*)&As[row * 64 + ((((kk >> 3) + lg) ^ (row & 7)) << 3)];
      }
#pragma unroll
      for (int j = 0; j < 4; ++j) {
        const int row = wc + j * 16 + lr;
        bfr[j] = *(const bf16x8*)&Bs[row * 64 + ((((kk >> 3) + lg) ^ (row & 7)) << 3)];
      }
#pragma unroll
      for (int i = 0; i < 4; ++i)
#pragma unroll
        for (int j = 0; j < 4; ++j)
          acc[i][j] = __builtin_amdgcn_mfma_f32_16x16x32_bf16(af[i], bfr[j], acc[i][j], 0, 0, 0);
    }
  }

#pragma unroll
  for (int i = 0; i < 4; ++i) {
    const int row0 = bm + wr + i * 16 + lg * 4;
#pragma unroll
    for (int j = 0; j < 4; ++j) {
      const int col = bn + wc + j * 16 + lr;
      const float bb = bias0[col] + bias1[col];
#pragma unroll
      for (int r = 0; r < 4; ++r) {
        const size_t o = (size_t)(row0 + r) * 512 + col;
        Cf[o] = acc[i][j][r] + bb + b2f(init16[o]);
      }
    }
  }
}

// ------- fused attention (R8 best): GN folded; V-half0 prefetch; nontemporal P stores ------
__global__ __launch_bounds__(256) void attn_fused(const unsigned short* __restrict__ q16,
                                                  const unsigned short* __restrict__ k16,
                                                  const unsigned short* __restrict__ vT,
                                                  const float* __restrict__ part_q,
                                                  const float* __restrict__ part_k,
                                                  const float* __restrict__ sk,
                                                  float* __restrict__ aw,
                                                  unsigned short* __restrict__ ao16) {
  __shared__ __align__(16) unsigned short Qs[64 * 64];
  __shared__ __align__(16) unsigned short Ks[256 * 64];
  __shared__ __align__(16) unsigned short Ps[64 * 256];
  __shared__ float WM[4][64];
  __shared__ float WS[4][64];
  __shared__ float sk_lds[512];
  __shared__ float cst[2];

  const int bid = blockIdx.x;
  const int q0 = blockIdx.y << 6;
  const int h = bid & 7;
  const int b = bid >> 6;
  const int tid = threadIdx.x;
  const int w = tid >> 6, lane = tid & 63;
  const int lr = lane & 15, lg = lane >> 4;
  const int srow = lane >> 3;
  const int sslot = (lane & 7) ^ srow;

  const size_t hb = (size_t)(bid >> 3) * (512 * 512);
  const unsigned short* Qg = q16 + hb + h * 64;
  const unsigned short* Kg = k16 + hb + h * 64;
  const unsigned short* Vg = vT + hb + (size_t)h * 64 * 512;

  if (tid == 0) {
    const int pbase = (((b << 2) | (h >> 1)) << 6);
    const float* pq = part_q + pbase;
    const float* pk = part_k + pbase;
    float Sq = 0.f, SQq = 0.f, Sk = 0.f, SQk = 0.f;
    for (int c = 0; c < 32; ++c) {
      Sq += pq[c * 2]; SQq += pq[c * 2 + 1];
      Sk += pk[c * 2]; SQk += pk[c * 2 + 1];
    }
    const float inv = 1.f / (float)(NTROWS * 128);
    const float muq = Sq * inv, vq = SQq * inv - muq * muq;
    const float muk = Sk * inv, vk = SQk * inv - muk * muk;
    const float a = rsqrtf(vq + EPSGN) * rsqrtf(vk + EPSGN) * 0.125f;
    cst[0] = a;
    cst[1] = a * muq;
  }
  {
    const float* skg = sk + (size_t)(bid >> 3) * 512 * 8 + h;
    for (int j = tid; j < 512; j += 256) sk_lds[j] = skg[(size_t)j * 8];
  }

#pragma unroll
  for (int it = 0; it < 2; ++it) {  // stage Q 64x64 async
    const int ci = w * 2 + it;
    const int row = ci * 8 + srow;
    GLOAD16(Qg + (size_t)(q0 + row) * 512 + sslot * 8, (char*)Qs + ci * 1024);
  }

  f32x4 sc[4][8] = {};

#pragma unroll
  for (int half = 0; half < 2; ++half) {
    __syncthreads();
#pragma unroll
    for (int it = 0; it < 8; ++it) {  // stage K half (per-wave region) async
      const int ci = w * 8 + it;
      const int row = ci * 8 + srow;
      GLOAD16(Kg + (size_t)(half * 256 + row) * 512 + sslot * 8, (char*)Ks + ci * 1024);
    }
    __syncthreads();
#pragma unroll
    for (int kk = 0; kk < 64; kk += 32) {
      bf16x8 aq[4];
#pragma unroll
      for (int qf = 0; qf < 4; ++qf) {
        const int row = qf * 16 + lr;
        aq[qf] = *(const bf16x8*)&Qs[row * 64 + ((((kk >> 3) + lg) ^ (row & 7)) << 3)];
      }
#pragma unroll
      for (int kf = 0; kf < 4; ++kf) {
        const int row = w * 64 + kf * 16 + lr;
        const bf16x8 bk = *(const bf16x8*)&Ks[row * 64 + ((((kk >> 3) + lg) ^ (row & 7)) << 3)];
#pragma unroll
        for (int qf = 0; qf < 4; ++qf)
          sc[qf][half * 4 + kf] =
              __builtin_amdgcn_mfma_f32_16x16x32_bf16(aq[qf], bk, sc[qf][half * 4 + kf], 0, 0, 0);
      }
    }
  }

  // issue V half0 into this wave's own Ks region (QK ds_reads complete; no cross-wave reads)
#pragma unroll
  for (int it = 0; it < 8; ++it) {
    const int ci = w * 8 + it;
    const int row = ci * 2 + (lane >> 5);
    const int s = lane & 31;
    GLOAD16(Vg + (size_t)row * 512 + ((s ^ (row & 7)) << 3), (char*)Ks + ci * 1024);
  }

  // ---- GN correction: logit = a*S - a*mu_q*Sk[col] ----
  const float aSc = cst[0], cmu = cst[1];
#pragma unroll
  for (int qf = 0; qf < 4; ++qf)
#pragma unroll
    for (int kfi = 0; kfi < 8; ++kfi) {
      const int k = ((kfi >> 2) << 8) + w * 64 + ((kfi & 3) << 4) + lr;
      const float corr = cmu * sk_lds[k];
#pragma unroll
      for (int r = 0; r < 4; ++r) sc[qf][kfi][r] = aSc * sc[qf][kfi][r] - corr;
    }

  // ---- softmax ----
  float Mv[4][4];
#pragma unroll
  for (int qf = 0; qf < 4; ++qf)
#pragma unroll
    for (int r = 0; r < 4; ++r) {
      float m = sc[qf][0][r];
#pragma unroll
      for (int kf = 1; kf < 8; ++kf) m = fmaxf(m, sc[qf][kf][r]);
#pragma unroll
      for (int o = 1; o < 16; o <<= 1) m = fmaxf(m, __shfl_xor(m, o));
      Mv[qf][r] = m;
    }
  if (lr == 0) {
#pragma unroll
    for (int qf = 0; qf < 4; ++qf)
#pragma unroll
      for (int r = 0; r < 4; ++r) WM[w][qf * 16 + lg * 4 + r] = Mv[qf][r];
  }
  __syncthreads();
#pragma unroll
  for (int qf = 0; qf < 4; ++qf)
#pragma unroll
    for (int r = 0; r < 4; ++r) {
      const int q = qf * 16 + lg * 4 + r;
      Mv[qf][r] = fmaxf(fmaxf(WM[0][q], WM[1][q]), fmaxf(WM[2][q], WM[3][q]));
    }
  float sl[4][4] = {};
#pragma unroll
  for (int qf = 0; qf < 4; ++qf)
#pragma unroll
    for (int kf = 0; kf < 8; ++kf) {
      f32x4 v = sc[qf][kf];
#pragma unroll
      for (int r = 0; r < 4; ++r) {
        const float e = __expf(v[r] - Mv[qf][r]);
        v[r] = e;
        sl[qf][r] += e;
      }
      sc[qf][kf] = v;
    }
#pragma unroll
  for (int qf = 0; qf < 4; ++qf)
#pragma unroll
    for (int r = 0; r < 4; ++r) {
      float s = sl[qf][r];
#pragma unroll
      for (int o = 1; o < 16; o <<= 1) s += __shfl_xor(s, o);
      sl[qf][r] = s;
    }
  if (lr == 0) {
#pragma unroll
    for (int qf = 0; qf < 4; ++qf)
#pragma unroll
      for (int r = 0; r < 4; ++r) WS[w][qf * 16 + lg * 4 + r] = sl[qf][r];
  }
  __syncthreads();
#pragma unroll
  for (int qf = 0; qf < 4; ++qf)
#pragma unroll
    for (int r = 0; r < 4; ++r) {
      const int q = qf * 16 + lg * 4 + r;
      const float inv = 1.f / (WS[0][q] + WS[1][q] + WS[2][q] + WS[3][q]);
#pragma unroll
      for (int kf = 0; kf < 8; ++kf) sc[qf][kf][r] *= inv;
    }

  // ---- write P (fp32, nontemporal: keep the 268MB stream out of L2) ----
  float* AWp = aw + ((size_t)bid * 512 + q0) * 512;
#pragma unroll
  for (int qf = 0; qf < 4; ++qf)
#pragma unroll
    for (int kfi = 0; kfi < 8; ++kfi) {
      const int k = ((kfi >> 2) << 8) + w * 64 + ((kfi & 3) << 4) + lr;
#pragma unroll
      for (int r = 0; r < 4; ++r)
        __builtin_nontemporal_store(sc[qf][kfi][r],
                                    &AWp[(size_t)(qf * 16 + lg * 4 + r) * 512 + k]);
    }

  // ---- stage P half0 (bf16) swizzled ----
#pragma unroll
  for (int qf = 0; qf < 4; ++qf)
#pragma unroll
    for (int r = 0; r < 4; ++r) {
      const int q = qf * 16 + lg * 4 + r;
#pragma unroll
      for (int kf = 0; kf < 4; ++kf) {
        const int k = w * 64 + (kf << 4) + lr;
        Ps[q * 256 + (((k >> 3) ^ (q & 7)) << 3) + (k & 7)] = f2b(sc[qf][kf][r]);
      }
    }
  __syncthreads();  // V0 (vmcnt) + Ps0 (lgkm) complete for all waves

  f32x4 accO[4] = {};
#pragma unroll
  for (int ks = 0; ks < 256; ks += 32) {
    const int sl0 = ks >> 3;
    const int q = w * 16 + lr;
    const bf16x8 af = *(const bf16x8*)&Ps[q * 256 + (((sl0 + lg) ^ (q & 7)) << 3)];
#pragma unroll
    for (int df = 0; df < 4; ++df) {
      const int row = df * 16 + lr;
      const bf16x8 vb = *(const bf16x8*)&Ks[row * 256 + (((sl0 + lg) ^ (row & 7)) << 3)];
      accO[df] = __builtin_amdgcn_mfma_f32_16x16x32_bf16(af, vb, accO[df], 0, 0, 0);
    }
  }
  __syncthreads();  // all waves done reading V0/Ps0

  // issue V half1 + stage P half1
#pragma unroll
  for (int it = 0; it < 8; ++it) {
    const int ci = w * 8 + it;
    const int row = ci * 2 + (lane >> 5);
    const int s = lane & 31;
    GLOAD16(Vg + (size_t)row * 512 + 256 + ((s ^ (row & 7)) << 3), (char*)Ks + ci * 1024);
  }
#pragma unroll
  for (int qf = 0; qf < 4; ++qf)
#pragma unroll
    for (int r = 0; r < 4; ++r) {
      const int q = qf * 16 + lg * 4 + r;
#pragma unroll
      for (int kf = 0; kf < 4; ++kf) {
        const int k = w * 64 + (kf << 4) + lr;
        Ps[q * 256 + (((k >> 3) ^ (q & 7)) << 3) + (k & 7)] = f2b(sc[qf][4 + kf][r]);
      }
    }
  __syncthreads();

#pragma unroll
  for (int ks = 0; ks < 256; ks += 32) {
    const int sl0 = ks >> 3;
    const int q = w * 16 + lr;
    const bf16x8 af = *(const bf16x8*)&Ps[q * 256 + (((sl0 + lg) ^ (q & 7)) << 3)];
#pragma unroll
    for (int df = 0; df < 4; ++df) {
      const int row = df * 16 + lr;
      const bf16x8 vb = *(const bf16x8*)&Ks[row * 256 + (((sl0 + lg) ^ (row & 7)) << 3)];
      accO[df] = __builtin_amdgcn_mfma_f32_16x16x32_bf16(af, vb, accO[df], 0, 0, 0);
    }
  }

  const int growb = (bid >> 3) * 512 + q0 + w * 16 + lg * 4;
#pragma unroll
  for (int df = 0; df < 4; ++df)
#pragma unroll
    for (int r = 0; r < 4; ++r)
      ao16[(size_t)(growb + r) * 512 + h * 64 + df * 16 + lr] = f2b(accO[df][r]);
}

// ---------------- launcher ----------------
extern "C" void kernel_launch(void* const* d_in, const int* in_sizes, int n_in,
                              void* d_out, int out_size, void* d_ws, size_t ws_size,
                              hipStream_t stream) {
  const float* in_f = (const float*)d_in[1];
  const float* in_fkv = (const float*)d_in[2];
  const float* Wq = (const float*)d_in[3];
  const float* Wk = (const float*)d_in[4];
  const float* Wv = (const float*)d_in[5];
  const float* Wz = (const float*)d_in[6];
  const float* bz = (const float*)d_in[7];
  const float* W1 = (const float*)d_in[8];
  const float* b1 = (const float*)d_in[9];
  const float* W2 = (const float*)d_in[10];
  const float* b2 = (const float*)d_in[11];

  float* out_f = (float*)d_out;
  float* attw = out_f + (size_t)MROWS * DDIM;

  const size_t TSB = (size_t)MROWS * DDIM;
  unsigned short* us = (unsigned short*)d_ws;
  unsigned short* a16 = us;
  unsigned short* akv16 = us + TSB;
  unsigned short* q16 = us + 2 * TSB;
  unsigned short* k16 = us + 3 * TSB;
  unsigned short* h16 = us + 4 * TSB;
  unsigned short* ao16 = us + 5 * TSB;
  unsigned short* vT = us + 6 * TSB;
  unsigned short* w16s = us + 7 * TSB;
  float* fbase = (float*)(us + 7 * TSB + 18 * 262144);
  float* p0 = fbase;
  float* p1 = fbase + 4096;
  float* part_q = fbase + 8192;
  float* part_k = fbase + 9216;
  float* corr = fbase + 10240;
  float* sk = fbase + 18432;

  stats_cvt<<<dim3(512, 3), 256, 0, stream>>>(in_f, in_fkv, a16, akv16, p0, p1, Wz, W2, w16s);
  wprep<<<dim3(128, 16), 256, 0, stream>>>(Wq, Wk, Wv, W1, p0, p1, w16s, corr);
  gemm_all<<<dim3(128, 8, 2), 256, 0, stream>>>(a16, akv16, w16s, corr, q16, h16, k16, vT, b1,
                                                part_q, part_k, sk);
  attn_fused<<<dim3(256, 8), 256, 0, stream>>>(q16, k16, vT, part_q, part_k, sk, attw, ao16);
  gemm_final<<<dim3(128, 4), 256, 0, stream>>>(ao16, h16, w16s + 16 * 262144,
                                               w16s + 17 * 262144, out_f, bz, b2, a16);
}

// Round 13
// 237.531 us; speedup vs baseline: 1.1748x; 1.0030x over previous
//
#include <hip/hip_runtime.h>
#include <math.h>

#define TDIM 512
#define DDIM 512
#define NTROWS 4096
#define MROWS 16384
#define EPSGN 1e-3f

typedef __attribute__((ext_vector_type(8))) short bf16x8;
typedef __attribute__((ext_vector_type(4))) float f32x4;
typedef __attribute__((ext_vector_type(8))) unsigned short us8;
typedef __attribute__((ext_vector_type(4))) unsigned short us4;

__device__ __forceinline__ unsigned short f2b(float f) {
  unsigned int u = __float_as_uint(f);
  return (unsigned short)((u + 0x7fffu + ((u >> 16) & 1u)) >> 16);
}
__device__ __forceinline__ float b2f(unsigned short h) {
  return __uint_as_float(((unsigned int)h) << 16);
}

#define GLOAD16(g, l)                                                                   \
  __builtin_amdgcn_global_load_lds((const __attribute__((address_space(1))) void*)(g),  \
                                   (__attribute__((address_space(3))) void*)(l), 16, 0, 0)

// ------- fused: fp32 -> raw bf16 convert + GroupNorm partial stats (+ Wz/W2 convert) -------
__global__ __launch_bounds__(256) void stats_cvt(const float* __restrict__ x0,
                                                 const float* __restrict__ x1,
                                                 unsigned short* __restrict__ o0,
                                                 unsigned short* __restrict__ o1,
                                                 float* __restrict__ p0,
                                                 float* __restrict__ p1,
                                                 const float* __restrict__ Wz,
                                                 const float* __restrict__ W2,
                                                 unsigned short* __restrict__ w16s) {
  if (blockIdx.y == 2) {
    const int bid = blockIdx.x;
    if (bid >= 256) return;
    const int c = bid * 256 + threadIdx.x;
    const int t = c >> 15;
    const int off = c & 32767;
    const float* s = t ? W2 : Wz;
    unsigned short* d = w16s + (size_t)(16 + t) * 262144;
    const float4 f0 = *(const float4*)(s + (size_t)off * 8);
    const float4 f1 = *(const float4*)(s + (size_t)off * 8 + 4);
    us8 v;
    v[0] = f2b(f0.x); v[1] = f2b(f0.y); v[2] = f2b(f0.z); v[3] = f2b(f0.w);
    v[4] = f2b(f1.x); v[5] = f2b(f1.y); v[6] = f2b(f1.z); v[7] = f2b(f1.w);
    *(us8*)(d + (size_t)off * 8) = v;
    return;
  }
  const float* x = blockIdx.y ? x1 : x0;
  unsigned short* o = blockIdx.y ? o1 : o0;
  float* part = blockIdx.y ? p1 : p0;
  const int blk = blockIdx.x;
  const int batch = blk >> 7;
  const int chunk = blk & 127;
  const size_t base = (size_t)blk * 32 * 512;
  const int tid = threadIdx.x;
  float s = 0.f, sq = 0.f;
#pragma unroll 4
  for (int it = 0; it < 8; ++it) {
    const size_t e = base + (size_t)it * 2048 + (size_t)tid * 8;
    const float4 f0 = *(const float4*)(x + e);
    const float4 f1 = *(const float4*)(x + e + 4);
    us8 v;
    v[0] = f2b(f0.x); v[1] = f2b(f0.y); v[2] = f2b(f0.z); v[3] = f2b(f0.w);
    v[4] = f2b(f1.x); v[5] = f2b(f1.y); v[6] = f2b(f1.z); v[7] = f2b(f1.w);
    *(us8*)(o + e) = v;
    s += f0.x + f0.y + f0.z + f0.w + f1.x + f1.y + f1.z + f1.w;
    sq += f0.x * f0.x + f0.y * f0.y + f0.z * f0.z + f0.w * f0.w +
          f1.x * f1.x + f1.y * f1.y + f1.z * f1.z + f1.w * f1.w;
  }
  const int wave = tid >> 6, lane = tid & 63;
#pragma unroll
  for (int of = 1; of < 16; of <<= 1) { s += __shfl_xor(s, of); sq += __shfl_xor(sq, of); }
  __shared__ float red[4][4][2];
  if ((lane & 15) == 0) { red[wave][lane >> 4][0] = s; red[wave][lane >> 4][1] = sq; }
  __syncthreads();
  if (tid < 4) {
    float S = 0.f, SQ = 0.f;
#pragma unroll
    for (int w = 0; w < 4; ++w) { S += red[w][tid][0]; SQ += red[w][tid][1]; }
    const int idx = (((batch << 2) | tid) << 7) | chunk;
    part[idx * 2] = S;
    part[idx * 2 + 1] = SQ;
  }
}

// ---------------- weight prep: per-batch GN-scaled weights + column corrections ------------
__global__ __launch_bounds__(256) void wprep(const float* __restrict__ Wq,
                                             const float* __restrict__ Wk,
                                             const float* __restrict__ Wv,
                                             const float* __restrict__ W1,
                                             const float* __restrict__ p0,
                                             const float* __restrict__ p1,
                                             unsigned short* __restrict__ w16s,
                                             float* __restrict__ corr) {
  const int y = blockIdx.y;
  const int w = y >> 2, b = y & 3;
  const float* W = (w == 0) ? Wq : (w == 1) ? Wk : (w == 2) ? Wv : W1;
  const float* part = (w == 0 || w == 3) ? p0 : p1;
  __shared__ float mrs[4][2];
  if (threadIdx.x < 4) {
    const float* p = part + (((b << 2) | threadIdx.x) << 7) * 2;
    float S = 0.f, SQ = 0.f;
    for (int c = 0; c < 128; ++c) { S += p[c * 2]; SQ += p[c * 2 + 1]; }
    const float inv = 1.f / (float)(NTROWS * 128);
    const float mu = S * inv;
    const float var = SQ * inv - mu * mu;
    const float rs = rsqrtf(var + EPSGN);
    mrs[threadIdx.x][0] = rs;
    mrs[threadIdx.x][1] = mu * rs;
  }
  __syncthreads();
  const int wave = threadIdx.x >> 6, lane = threadIdx.x & 63;
  const int n = blockIdx.x * 4 + wave;
  const int k = lane * 8;
  const int g = lane >> 4;
  const float rs = mrs[g][0], murs = mrs[g][1];
  const float4 f0 = *(const float4*)(W + (size_t)n * 512 + k);
  const float4 f1 = *(const float4*)(W + (size_t)n * 512 + k + 4);
  us8 v;
  v[0] = f2b(f0.x * rs); v[1] = f2b(f0.y * rs); v[2] = f2b(f0.z * rs); v[3] = f2b(f0.w * rs);
  v[4] = f2b(f1.x * rs); v[5] = f2b(f1.y * rs); v[6] = f2b(f1.z * rs); v[7] = f2b(f1.w * rs);
  *(us8*)(w16s + (size_t)((w << 2) | b) * 262144 + (size_t)n * 512 + k) = v;
  float t = (f0.x + f0.y + f0.z + f0.w + f1.x + f1.y + f1.z + f1.w) * murs;
#pragma unroll
  for (int of = 1; of < 64; of <<= 1) t += __shfl_xor(t, of);
  if (lane == 0) corr[(((w << 2) | b) << 9) | n] = t;
}

// ---------------- unified projection GEMMs (grid (128,8,2), XCD-swizzled) ----------------
__global__ __launch_bounds__(256) void gemm_all(const unsigned short* __restrict__ a16,
                                                const unsigned short* __restrict__ akv16,
                                                const unsigned short* __restrict__ w16s,
                                                const float* __restrict__ corr,
                                                unsigned short* __restrict__ q16,
                                                unsigned short* __restrict__ h16,
                                                unsigned short* __restrict__ k16,
                                                unsigned short* __restrict__ vTb,
                                                const float* __restrict__ b1,
                                                float* __restrict__ part_q,
                                                float* __restrict__ part_k,
                                                float* __restrict__ sk) {
  __shared__ __align__(16) unsigned short As[128 * 64];
  __shared__ __align__(16) unsigned short Bs[128 * 64];
  __shared__ float red[8];
  const int p = blockIdx.x + (blockIdx.y << 7) + (blockIdx.z << 10);
  const int xc = p & 7, m = p >> 3;
  const int bxi = (xc << 4) | (m & 15);
  const int yi = (m >> 4) & 7;
  const int z = m >> 7;
  const int tid = threadIdx.x;
  const int wave = tid >> 6, lane = tid & 63;
  const int bm = bxi << 7;
  const int batch = bxi >> 5;
  const bool first = yi < 4;
  const int widx = z ? (first ? 1 : 2) : (first ? 0 : 3);
  const unsigned short* A = z ? akv16 : a16;
  const unsigned short* B = w16s + (size_t)262144 * ((widx << 2) | batch);
  const int bnl = (yi & 3) << 7;
  const int wr = (wave >> 1) << 6;
  const int wc = (wave & 1) << 6;
  const int lr = lane & 15, lg = lane >> 4;

  f32x4 acc[4][4] = {};
  const int srow = lane >> 3;
  const int sslot = (lane & 7) ^ srow;

  for (int k0 = 0; k0 < 512; k0 += 64) {
    __syncthreads();
#pragma unroll
    for (int i = 0; i < 4; ++i) {
      const int ci = wave * 4 + i;
      const int row = ci * 8 + srow;
      GLOAD16(A + (size_t)(bm + row) * 512 + k0 + sslot * 8, (char*)As + ci * 1024);
      GLOAD16(B + (size_t)(bnl + row) * 512 + k0 + sslot * 8, (char*)Bs + ci * 1024);
    }
    __syncthreads();
#pragma unroll
    for (int kk = 0; kk < 64; kk += 32) {
      bf16x8 af[4], bfr[4];
#pragma unroll
      for (int i = 0; i < 4; ++i) {
        const int row = wr + i * 16 + lr;
        af[i] = *(const bf16x8*)&As[row * 64 + ((((kk >> 3) + lg) ^ (row & 7)) << 3)];
      }
#pragma unroll
      for (int j = 0; j < 4; ++j) {
        const int row = wc + j * 16 + lr;
        bfr[j] = *(const bf16x8*)&Bs[row * 64 + ((((kk >> 3) + lg) ^ (row & 7)) << 3)];
      }
#pragma unroll
      for (int i = 0; i < 4; ++i)
#pragma unroll
        for (int j = 0; j < 4; ++j)
          acc[i][j] = __builtin_amdgcn_mfma_f32_16x16x32_bf16(af[i], bfr[j], acc[i][j], 0, 0, 0);
    }
  }

  {
    const float* cb = corr + (((widx << 2) | batch) << 9);
    float cj[4];
#pragma unroll
    for (int j = 0; j < 4; ++j) cj[j] = cb[bnl + wc + j * 16 + lr];
#pragma unroll
    for (int i = 0; i < 4; ++i)
#pragma unroll
      for (int j = 0; j < 4; ++j)
#pragma unroll
        for (int r = 0; r < 4; ++r) acc[i][j][r] -= cj[j];
  }

  if (first) {
    unsigned short* C0 = z ? k16 : q16;
#pragma unroll
    for (int i = 0; i < 4; ++i) {
      const int row0 = bm + wr + i * 16 + lg * 4;
#pragma unroll
      for (int j = 0; j < 4; ++j) {
        const int col = bnl + wc + j * 16 + lr;
#pragma unroll
        for (int r = 0; r < 4; ++r)
          C0[(size_t)(row0 + r) * 512 + col] = f2b(acc[i][j][r]);
      }
    }
    float s = 0.f, sq = 0.f;
#pragma unroll
    for (int i = 0; i < 4; ++i)
#pragma unroll
      for (int j = 0; j < 4; ++j)
#pragma unroll
        for (int r = 0; r < 4; ++r) { const float v = acc[i][j][r]; s += v; sq += v * v; }
#pragma unroll
    for (int o = 32; o > 0; o >>= 1) { s += __shfl_xor(s, o); sq += __shfl_xor(sq, o); }
    if (lane == 0) { red[wave * 2] = s; red[wave * 2 + 1] = sq; }
    __syncthreads();
    if (tid == 0) {
      float* part = z ? part_k : part_q;
      const float S = red[0] + red[2] + red[4] + red[6];
      const float SQ = red[1] + red[3] + red[5] + red[7];
      const int slot = bxi & 31, g = yi;
      const int idx = ((((batch << 2) | g) << 5) | slot) << 1;
      part[idx] = S;
      part[idx + 1] = SQ;
    }
    if (z) {
      const int head = (bnl >> 6) + (wave & 1);
#pragma unroll
      for (int i = 0; i < 4; ++i) {
#pragma unroll
        for (int r = 0; r < 4; ++r) {
          float t = acc[i][0][r] + acc[i][1][r] + acc[i][2][r] + acc[i][3][r];
#pragma unroll
          for (int o = 1; o < 16; o <<= 1) t += __shfl_xor(t, o);
          if (lr == 0)
            sk[(size_t)(bm + wr + i * 16 + lg * 4 + r) * 8 + head] = t;
        }
      }
    }
  } else if (z == 0) {
#pragma unroll
    for (int i = 0; i < 4; ++i) {
      const int row0 = bm + wr + i * 16 + lg * 4;
#pragma unroll
      for (int j = 0; j < 4; ++j) {
        const int col = bnl + wc + j * 16 + lr;
        const float bb = b1[col];
#pragma unroll
        for (int r = 0; r < 4; ++r) {
          float v = acc[i][j][r] + bb;
          v = v > 0.f ? v : 0.01f * v;
          h16[(size_t)(row0 + r) * 512 + col] = f2b(v);
        }
      }
    }
  } else {
#pragma unroll
    for (int i = 0; i < 4; ++i) {
      const int row0 = bm + wr + i * 16 + lg * 4;
#pragma unroll
      for (int j = 0; j < 4; ++j) {
        const int col = bnl + wc + j * 16 + lr;
        us4 pk;
#pragma unroll
        for (int r = 0; r < 4; ++r) pk[r] = f2b(acc[i][j][r]);
        *(us4*)&vTb[((size_t)(row0 >> 9) * 512 + col) * 512 + (row0 & 511)] = pk;
      }
    }
  }
}

// -------- final GEMM (grid (128,4), XCD-swizzled): out = [ao|h1] @ [Wz|W2]^T + ... --------
__global__ __launch_bounds__(256) void gemm_final(const unsigned short* __restrict__ A0,
                                                  const unsigned short* __restrict__ A1,
                                                  const unsigned short* __restrict__ B0,
                                                  const unsigned short* __restrict__ B1,
                                                  float* __restrict__ Cf,
                                                  const float* __restrict__ bias0,
                                                  const float* __restrict__ bias1,
                                                  const unsigned short* __restrict__ init16) {
  __shared__ __align__(16) unsigned short As[128 * 64];
  __shared__ __align__(16) unsigned short Bs[128 * 64];
  const int p = blockIdx.x + (blockIdx.y << 7);
  const int xc = p & 7, m = p >> 3;
  const int bxi = (xc << 4) | (m & 15);
  const int bni = (m >> 4) & 3;
  const int tid = threadIdx.x;
  const int wave = tid >> 6, lane = tid & 63;
  const int bm = bxi << 7, bn = bni << 7;
  const int wr = (wave >> 1) << 6;
  const int wc = (wave & 1) << 6;
  const int lr = lane & 15, lg = lane >> 4;

  f32x4 acc[4][4] = {};
  const int srow = lane >> 3;
  const int sslot = (lane & 7) ^ srow;

  for (int k0 = 0; k0 < 1024; k0 += 64) {
    const unsigned short* Ab = (k0 < 512) ? A0 : A1;
    const unsigned short* Bb = (k0 < 512) ? B0 : B1;
    const int kl = k0 & 511;
    __syncthreads();
#pragma unroll
    for (int i = 0; i < 4; ++i) {
      const int ci = wave * 4 + i;
      const int row = ci * 8 + srow;
      GLOAD16(Ab + (size_t)(bm + row) * 512 + kl + sslot * 8, (char*)As + ci * 1024);
      GLOAD16(Bb + (size_t)(bn + row) * 512 + kl + sslot * 8, (char*)Bs + ci * 1024);
    }
    __syncthreads();
#pragma unroll
    for (int kk = 0; kk < 64; kk += 32) {
      bf16x8 af[4], bfr[4];
#pragma unroll
      for (int i = 0; i < 4; ++i) {
        const int row = wr + i * 16 + lr;
        af[i] = *(const bf16x8*)&As[row * 64 + ((((kk >> 3) + lg) ^ (row & 7)) << 3)];
      }
#pragma unroll
      for (int j = 0; j < 4; ++j) {
        const int row = wc + j * 16 + lr;
        bfr[j] = *(const bf16x8*)&Bs[row * 64 + ((((kk >> 3) + lg) ^ (row & 7)) << 3)];
      }
#pragma unroll
      for (int i = 0; i < 4; ++i)
#pragma unroll
        for (int j = 0; j < 4; ++j)
          acc[i][j] = __builtin_amdgcn_mfma_f32_16x16x32_bf16(af[i], bfr[j], acc[i][j], 0, 0, 0);
    }
  }

#pragma unroll
  for (int i = 0; i < 4; ++i) {
    const int row0 = bm + wr + i * 16 + lg * 4;
#pragma unroll
    for (int j = 0; j < 4; ++j) {
      const int col = bn + wc + j * 16 + lr;
      const float bb = bias0[col] + bias1[col];
#pragma unroll
      for (int r = 0; r < 4; ++r) {
        const size_t o = (size_t)(row0 + r) * 512 + col;
        Cf[o] = acc[i][j][r] + bb + b2f(init16[o]);
      }
    }
  }
}

// ------- fused attention: GN folded; LDS-transposed coalesced nt P-write -------
__global__ __launch_bounds__(256) void attn_fused(const unsigned short* __restrict__ q16,
                                                  const unsigned short* __restrict__ k16,
                                                  const unsigned short* __restrict__ vT,
                                                  const float* __restrict__ part_q,
                                                  const float* __restrict__ part_k,
                                                  const float* __restrict__ sk,
                                                  float* __restrict__ aw,
                                                  unsigned short* __restrict__ ao16) {
  // manual union: [Qs 8KB | Ks 32KB | Ps 32KB] overlaid with Pf fp32[64][260] (66.5KB)
  __shared__ __align__(16) char smem[73728];
  unsigned short* Qs = (unsigned short*)smem;            // [64*64]
  unsigned short* Ks = (unsigned short*)(smem + 8192);   // [256*64] (K tiles; later V)
  unsigned short* Ps = (unsigned short*)(smem + 40960);  // [64*256]
  float* Pf = (float*)smem;                              // [64][260] staging for P-write
  __shared__ float WM[4][64];
  __shared__ float WS[4][64];
  __shared__ float sk_lds[512];
  __shared__ float cst[2];

  const int bid = blockIdx.x;
  const int q0 = blockIdx.y << 6;
  const int h = bid & 7;
  const int b = bid >> 6;
  const int tid = threadIdx.x;
  const int w = tid >> 6, lane = tid & 63;
  const int lr = lane & 15, lg = lane >> 4;
  const int srow = lane >> 3;
  const int sslot = (lane & 7) ^ srow;

  const size_t hb = (size_t)(bid >> 3) * (512 * 512);
  const unsigned short* Qg = q16 + hb + h * 64;
  const unsigned short* Kg = k16 + hb + h * 64;
  const unsigned short* Vg = vT + hb + (size_t)h * 64 * 512;

  if (tid == 0) {
    const int pbase = (((b << 2) | (h >> 1)) << 6);
    const float* pq = part_q + pbase;
    const float* pk = part_k + pbase;
    float Sq = 0.f, SQq = 0.f, Sk = 0.f, SQk = 0.f;
    for (int c = 0; c < 32; ++c) {
      Sq += pq[c * 2]; SQq += pq[c * 2 + 1];
      Sk += pk[c * 2]; SQk += pk[c * 2 + 1];
    }
    const float inv = 1.f / (float)(NTROWS * 128);
    const float muq = Sq * inv, vq = SQq * inv - muq * muq;
    const float muk = Sk * inv, vk = SQk * inv - muk * muk;
    const float a = rsqrtf(vq + EPSGN) * rsqrtf(vk + EPSGN) * 0.125f;
    cst[0] = a;
    cst[1] = a * muq;
  }
  {
    const float* skg = sk + (size_t)(bid >> 3) * 512 * 8 + h;
    for (int j = tid; j < 512; j += 256) sk_lds[j] = skg[(size_t)j * 8];
  }

#pragma unroll
  for (int it = 0; it < 2; ++it) {  // stage Q 64x64 async
    const int ci = w * 2 + it;
    const int row = ci * 8 + srow;
    GLOAD16(Qg + (size_t)(q0 + row) * 512 + sslot * 8, (char*)Qs + ci * 1024);
  }

  f32x4 sc[4][8] = {};

#pragma unroll
  for (int half = 0; half < 2; ++half) {
    __syncthreads();
#pragma unroll
    for (int it = 0; it < 8; ++it) {  // stage K half (per-wave region) async
      const int ci = w * 8 + it;
      const int row = ci * 8 + srow;
      GLOAD16(Kg + (size_t)(half * 256 + row) * 512 + sslot * 8, (char*)Ks + ci * 1024);
    }
    __syncthreads();
#pragma unroll
    for (int kk = 0; kk < 64; kk += 32) {
      bf16x8 aq[4];
#pragma unroll
      for (int qf = 0; qf < 4; ++qf) {
        const int row = qf * 16 + lr;
        aq[qf] = *(const bf16x8*)&Qs[row * 64 + ((((kk >> 3) + lg) ^ (row & 7)) << 3)];
      }
#pragma unroll
      for (int kf = 0; kf < 4; ++kf) {
        const int row = w * 64 + kf * 16 + lr;
        const bf16x8 bk = *(const bf16x8*)&Ks[row * 64 + ((((kk >> 3) + lg) ^ (row & 7)) << 3)];
#pragma unroll
        for (int qf = 0; qf < 4; ++qf)
          sc[qf][half * 4 + kf] =
              __builtin_amdgcn_mfma_f32_16x16x32_bf16(aq[qf], bk, sc[qf][half * 4 + kf], 0, 0, 0);
      }
    }
  }

  // ---- GN correction: logit = a*S - a*mu_q*Sk[col] ----
  const float aSc = cst[0], cmu = cst[1];
#pragma unroll
  for (int qf = 0; qf < 4; ++qf)
#pragma unroll
    for (int kfi = 0; kfi < 8; ++kfi) {
      const int k = ((kfi >> 2) << 8) + w * 64 + ((kfi & 3) << 4) + lr;
      const float corr = cmu * sk_lds[k];
#pragma unroll
      for (int r = 0; r < 4; ++r) sc[qf][kfi][r] = aSc * sc[qf][kfi][r] - corr;
    }

  // ---- softmax ----
  float Mv[4][4];
#pragma unroll
  for (int qf = 0; qf < 4; ++qf)
#pragma unroll
    for (int r = 0; r < 4; ++r) {
      float m = sc[qf][0][r];
#pragma unroll
      for (int kf = 1; kf < 8; ++kf) m = fmaxf(m, sc[qf][kf][r]);
#pragma unroll
      for (int o = 1; o < 16; o <<= 1) m = fmaxf(m, __shfl_xor(m, o));
      Mv[qf][r] = m;
    }
  if (lr == 0) {
#pragma unroll
    for (int qf = 0; qf < 4; ++qf)
#pragma unroll
      for (int r = 0; r < 4; ++r) WM[w][qf * 16 + lg * 4 + r] = Mv[qf][r];
  }
  __syncthreads();
#pragma unroll
  for (int qf = 0; qf < 4; ++qf)
#pragma unroll
    for (int r = 0; r < 4; ++r) {
      const int q = qf * 16 + lg * 4 + r;
      Mv[qf][r] = fmaxf(fmaxf(WM[0][q], WM[1][q]), fmaxf(WM[2][q], WM[3][q]));
    }
  float sl[4][4] = {};
#pragma unroll
  for (int qf = 0; qf < 4; ++qf)
#pragma unroll
    for (int kf = 0; kf < 8; ++kf) {
      f32x4 v = sc[qf][kf];
#pragma unroll
      for (int r = 0; r < 4; ++r) {
        const float e = __expf(v[r] - Mv[qf][r]);
        v[r] = e;
        sl[qf][r] += e;
      }
      sc[qf][kf] = v;
    }
#pragma unroll
  for (int qf = 0; qf < 4; ++qf)
#pragma unroll
    for (int r = 0; r < 4; ++r) {
      float s = sl[qf][r];
#pragma unroll
      for (int o = 1; o < 16; o <<= 1) s += __shfl_xor(s, o);
      sl[qf][r] = s;
    }
  if (lr == 0) {
#pragma unroll
    for (int qf = 0; qf < 4; ++qf)
#pragma unroll
      for (int r = 0; r < 4; ++r) WS[w][qf * 16 + lg * 4 + r] = sl[qf][r];
  }
  __syncthreads();
#pragma unroll
  for (int qf = 0; qf < 4; ++qf)
#pragma unroll
    for (int r = 0; r < 4; ++r) {
      const int q = qf * 16 + lg * 4 + r;
      const float inv = 1.f / (WS[0][q] + WS[1][q] + WS[2][q] + WS[3][q]);
#pragma unroll
      for (int kf = 0; kf < 8; ++kf) sc[qf][kf][r] *= inv;
    }

  // ---- P-write via LDS transpose: coalesced 16B/lane nontemporal stores ----
  // slot kfi = half*4+s2 holds column half*256 + (w*64 + s2*16 + lr) of P.
  float* AWp = aw + ((size_t)bid * 512 + q0) * 512;
#pragma unroll
  for (int half = 0; half < 2; ++half) {
#pragma unroll
    for (int qf = 0; qf < 4; ++qf)
#pragma unroll
      for (int s2 = 0; s2 < 4; ++s2) {
        const int kl = w * 64 + (s2 << 4) + lr;
#pragma unroll
        for (int r = 0; r < 4; ++r) {
          const int q = qf * 16 + lg * 4 + r;
          Pf[q * 260 + kl] = sc[qf][half * 4 + s2][r];
        }
      }
    __syncthreads();
#pragma unroll
    for (int rr = 0; rr < 16; ++rr) {
      const int q = w * 16 + rr;
      const f32x4 v = *(const f32x4*)&Pf[q * 260 + lane * 4];
      __builtin_nontemporal_store(
          v, (f32x4*)&AWp[(size_t)q * 512 + half * 256 + lane * 4]);
    }
    __syncthreads();
  }

  // ---- PV (Ks region now free again): V half0 + Ps half0 ----
#pragma unroll
  for (int it = 0; it < 8; ++it) {
    const int ci = w * 8 + it;
    const int row = ci * 2 + (lane >> 5);
    const int s = lane & 31;
    GLOAD16(Vg + (size_t)row * 512 + ((s ^ (row & 7)) << 3), (char*)Ks + ci * 1024);
  }
#pragma unroll
  for (int qf = 0; qf < 4; ++qf)
#pragma unroll
    for (int r = 0; r < 4; ++r) {
      const int q = qf * 16 + lg * 4 + r;
#pragma unroll
      for (int kf = 0; kf < 4; ++kf) {
        const int k = w * 64 + (kf << 4) + lr;
        Ps[q * 256 + (((k >> 3) ^ (q & 7)) << 3) + (k & 7)] = f2b(sc[qf][kf][r]);
      }
    }
  __syncthreads();  // V0 (vmcnt) + Ps0 (lgkm) complete for all waves

  f32x4 accO[4] = {};
#pragma unroll
  for (int ks = 0; ks < 256; ks += 32) {
    const int sl0 = ks >> 3;
    const int q = w * 16 + lr;
    const bf16x8 af = *(const bf16x8*)&Ps[q * 256 + (((sl0 + lg) ^ (q & 7)) << 3)];
#pragma unroll
    for (int df = 0; df < 4; ++df) {
      const int row = df * 16 + lr;
      const bf16x8 vb = *(const bf16x8*)&Ks[row * 256 + (((sl0 + lg) ^ (row & 7)) << 3)];
      accO[df] = __builtin_amdgcn_mfma_f32_16x16x32_bf16(af, vb, accO[df], 0, 0, 0);
    }
  }
  __syncthreads();  // all waves done reading V0/Ps0

  // V half1 + Ps half1
#pragma unroll
  for (int it = 0; it < 8; ++it) {
    const int ci = w * 8 + it;
    const int row = ci * 2 + (lane >> 5);
    const int s = lane & 31;
    GLOAD16(Vg + (size_t)row * 512 + 256 + ((s ^ (row & 7)) << 3), (char*)Ks + ci * 1024);
  }
#pragma unroll
  for (int qf = 0; qf < 4; ++qf)
#pragma unroll
    for (int r = 0; r < 4; ++r) {
      const int q = qf * 16 + lg * 4 + r;
#pragma unroll
      for (int kf = 0; kf < 4; ++kf) {
        const int k = w * 64 + (kf << 4) + lr;
        Ps[q * 256 + (((k >> 3) ^ (q & 7)) << 3) + (k & 7)] = f2b(sc[qf][4 + kf][r]);
      }
    }
  __syncthreads();

#pragma unroll
  for (int ks = 0; ks < 256; ks += 32) {
    const int sl0 = ks >> 3;
    const int q = w * 16 + lr;
    const bf16x8 af = *(const bf16x8*)&Ps[q * 256 + (((sl0 + lg) ^ (q & 7)) << 3)];
#pragma unroll
    for (int df = 0; df < 4; ++df) {
      const int row = df * 16 + lr;
      const bf16x8 vb = *(const bf16x8*)&Ks[row * 256 + (((sl0 + lg) ^ (row & 7)) << 3)];
      accO[df] = __builtin_amdgcn_mfma_f32_16x16x32_bf16(af, vb, accO[df], 0, 0, 0);
    }
  }

  const int growb = (bid >> 3) * 512 + q0 + w * 16 + lg * 4;
#pragma unroll
  for (int df = 0; df < 4; ++df)
#pragma unroll
    for (int r = 0; r < 4; ++r)
      ao16[(size_t)(growb + r) * 512 + h * 64 + df * 16 + lr] = f2b(accO[df][r]);
}

// ---------------- launcher ----------------
extern "C" void kernel_launch(void* const* d_in, const int* in_sizes, int n_in,
                              void* d_out, int out_size, void* d_ws, size_t ws_size,
                              hipStream_t stream) {
  const float* in_f = (const float*)d_in[1];
  const float* in_fkv = (const float*)d_in[2];
  const float* Wq = (const float*)d_in[3];
  const float* Wk = (const float*)d_in[4];
  const float* Wv = (const float*)d_in[5];
  const float* Wz = (const float*)d_in[6];
  const float* bz = (const float*)d_in[7];
  const float* W1 = (const float*)d_in[8];
  const float* b1 = (const float*)d_in[9];
  const float* W2 = (const float*)d_in[10];
  const float* b2 = (const float*)d_in[11];

  float* out_f = (float*)d_out;
  float* attw = out_f + (size_t)MROWS * DDIM;

  const size_t TSB = (size_t)MROWS * DDIM;
  unsigned short* us = (unsigned short*)d_ws;
  unsigned short* a16 = us;
  unsigned short* akv16 = us + TSB;
  unsigned short* q16 = us + 2 * TSB;
  unsigned short* k16 = us + 3 * TSB;
  unsigned short* h16 = us + 4 * TSB;
  unsigned short* ao16 = us + 5 * TSB;
  unsigned short* vT = us + 6 * TSB;
  unsigned short* w16s = us + 7 * TSB;
  float* fbase = (float*)(us + 7 * TSB + 18 * 262144);
  float* p0 = fbase;
  float* p1 = fbase + 4096;
  float* part_q = fbase + 8192;
  float* part_k = fbase + 9216;
  float* corr = fbase + 10240;
  float* sk = fbase + 18432;

  stats_cvt<<<dim3(512, 3), 256, 0, stream>>>(in_f, in_fkv, a16, akv16, p0, p1, Wz, W2, w16s);
  wprep<<<dim3(128, 16), 256, 0, stream>>>(Wq, Wk, Wv, W1, p0, p1, w16s, corr);
  gemm_all<<<dim3(128, 8, 2), 256, 0, stream>>>(a16, akv16, w16s, corr, q16, h16, k16, vT, b1,
                                                part_q, part_k, sk);
  attn_fused<<<dim3(256, 8), 256, 0, stream>>>(q16, k16, vT, part_q, part_k, sk, attw, ao16);
  gemm_final<<<dim3(128, 4), 256, 0, stream>>>(ao16, h16, w16s + 16 * 262144,
                                               w16s + 17 * 262144, out_f, bz, b2, a16);
}

// Round 14
// 230.162 us; speedup vs baseline: 1.2124x; 1.0320x over previous
//
#include <hip/hip_runtime.h>
#include <math.h>

#define TDIM 512
#define DDIM 512
#define NTROWS 4096
#define MROWS 16384
#define EPSGN 1e-3f

typedef __attribute__((ext_vector_type(8))) short bf16x8;
typedef __attribute__((ext_vector_type(4))) float f32x4;
typedef __attribute__((ext_vector_type(8))) unsigned short us8;
typedef __attribute__((ext_vector_type(4))) unsigned short us4;

__device__ __forceinline__ unsigned short f2b(float f) {
  unsigned int u = __float_as_uint(f);
  return (unsigned short)((u + 0x7fffu + ((u >> 16) & 1u)) >> 16);
}
__device__ __forceinline__ float b2f(unsigned short h) {
  return __uint_as_float(((unsigned int)h) << 16);
}

#define GLOAD16(g, l)                                                                   \
  __builtin_amdgcn_global_load_lds((const __attribute__((address_space(1))) void*)(g),  \
                                   (__attribute__((address_space(3))) void*)(l), 16, 0, 0)

// ------- fused: fp32 -> raw bf16 convert + GroupNorm partial stats (+ Wz/W2 convert) -------
__global__ __launch_bounds__(256) void stats_cvt(const float* __restrict__ x0,
                                                 const float* __restrict__ x1,
                                                 unsigned short* __restrict__ o0,
                                                 unsigned short* __restrict__ o1,
                                                 float* __restrict__ p0,
                                                 float* __restrict__ p1,
                                                 const float* __restrict__ Wz,
                                                 const float* __restrict__ W2,
                                                 unsigned short* __restrict__ w16s) {
  if (blockIdx.y == 2) {
    const int bid = blockIdx.x;
    if (bid >= 256) return;
    const int c = bid * 256 + threadIdx.x;
    const int t = c >> 15;
    const int off = c & 32767;
    const float* s = t ? W2 : Wz;
    unsigned short* d = w16s + (size_t)(16 + t) * 262144;
    const float4 f0 = *(const float4*)(s + (size_t)off * 8);
    const float4 f1 = *(const float4*)(s + (size_t)off * 8 + 4);
    us8 v;
    v[0] = f2b(f0.x); v[1] = f2b(f0.y); v[2] = f2b(f0.z); v[3] = f2b(f0.w);
    v[4] = f2b(f1.x); v[5] = f2b(f1.y); v[6] = f2b(f1.z); v[7] = f2b(f1.w);
    *(us8*)(d + (size_t)off * 8) = v;
    return;
  }
  const float* x = blockIdx.y ? x1 : x0;
  unsigned short* o = blockIdx.y ? o1 : o0;
  float* part = blockIdx.y ? p1 : p0;
  const int blk = blockIdx.x;
  const int batch = blk >> 7;
  const int chunk = blk & 127;
  const size_t base = (size_t)blk * 32 * 512;
  const int tid = threadIdx.x;
  float s = 0.f, sq = 0.f;
#pragma unroll 4
  for (int it = 0; it < 8; ++it) {
    const size_t e = base + (size_t)it * 2048 + (size_t)tid * 8;
    const float4 f0 = *(const float4*)(x + e);
    const float4 f1 = *(const float4*)(x + e + 4);
    us8 v;
    v[0] = f2b(f0.x); v[1] = f2b(f0.y); v[2] = f2b(f0.z); v[3] = f2b(f0.w);
    v[4] = f2b(f1.x); v[5] = f2b(f1.y); v[6] = f2b(f1.z); v[7] = f2b(f1.w);
    *(us8*)(o + e) = v;
    s += f0.x + f0.y + f0.z + f0.w + f1.x + f1.y + f1.z + f1.w;
    sq += f0.x * f0.x + f0.y * f0.y + f0.z * f0.z + f0.w * f0.w +
          f1.x * f1.x + f1.y * f1.y + f1.z * f1.z + f1.w * f1.w;
  }
  const int wave = tid >> 6, lane = tid & 63;
#pragma unroll
  for (int of = 1; of < 16; of <<= 1) { s += __shfl_xor(s, of); sq += __shfl_xor(sq, of); }
  __shared__ float red[4][4][2];
  if ((lane & 15) == 0) { red[wave][lane >> 4][0] = s; red[wave][lane >> 4][1] = sq; }
  __syncthreads();
  if (tid < 4) {
    float S = 0.f, SQ = 0.f;
#pragma unroll
    for (int w = 0; w < 4; ++w) { S += red[w][tid][0]; SQ += red[w][tid][1]; }
    const int idx = (((batch << 2) | tid) << 7) | chunk;
    part[idx * 2] = S;
    part[idx * 2 + 1] = SQ;
  }
}

// ---------------- weight prep: per-batch GN-scaled weights + column corrections ------------
__global__ __launch_bounds__(256) void wprep(const float* __restrict__ Wq,
                                             const float* __restrict__ Wk,
                                             const float* __restrict__ Wv,
                                             const float* __restrict__ W1,
                                             const float* __restrict__ p0,
                                             const float* __restrict__ p1,
                                             unsigned short* __restrict__ w16s,
                                             float* __restrict__ corr) {
  const int y = blockIdx.y;
  const int w = y >> 2, b = y & 3;
  const float* W = (w == 0) ? Wq : (w == 1) ? Wk : (w == 2) ? Wv : W1;
  const float* part = (w == 0 || w == 3) ? p0 : p1;
  __shared__ float mrs[4][2];
  if (threadIdx.x < 4) {
    const float* p = part + (((b << 2) | threadIdx.x) << 7) * 2;
    float S = 0.f, SQ = 0.f;
    for (int c = 0; c < 128; ++c) { S += p[c * 2]; SQ += p[c * 2 + 1]; }
    const float inv = 1.f / (float)(NTROWS * 128);
    const float mu = S * inv;
    const float var = SQ * inv - mu * mu;
    const float rs = rsqrtf(var + EPSGN);
    mrs[threadIdx.x][0] = rs;
    mrs[threadIdx.x][1] = mu * rs;
  }
  __syncthreads();
  const int wave = threadIdx.x >> 6, lane = threadIdx.x & 63;
  const int n = blockIdx.x * 4 + wave;
  const int k = lane * 8;
  const int g = lane >> 4;
  const float rs = mrs[g][0], murs = mrs[g][1];
  const float4 f0 = *(const float4*)(W + (size_t)n * 512 + k);
  const float4 f1 = *(const float4*)(W + (size_t)n * 512 + k + 4);
  us8 v;
  v[0] = f2b(f0.x * rs); v[1] = f2b(f0.y * rs); v[2] = f2b(f0.z * rs); v[3] = f2b(f0.w * rs);
  v[4] = f2b(f1.x * rs); v[5] = f2b(f1.y * rs); v[6] = f2b(f1.z * rs); v[7] = f2b(f1.w * rs);
  *(us8*)(w16s + (size_t)((w << 2) | b) * 262144 + (size_t)n * 512 + k) = v;
  float t = (f0.x + f0.y + f0.z + f0.w + f1.x + f1.y + f1.z + f1.w) * murs;
#pragma unroll
  for (int of = 1; of < 64; of <<= 1) t += __shfl_xor(t, of);
  if (lane == 0) corr[(((w << 2) | b) << 9) | n] = t;
}

// ---------------- unified projection GEMMs (grid (128,8,2), XCD-swizzled) ----------------
__global__ __launch_bounds__(256) void gemm_all(const unsigned short* __restrict__ a16,
                                                const unsigned short* __restrict__ akv16,
                                                const unsigned short* __restrict__ w16s,
                                                const float* __restrict__ corr,
                                                unsigned short* __restrict__ q16,
                                                unsigned short* __restrict__ h16,
                                                unsigned short* __restrict__ k16,
                                                unsigned short* __restrict__ vTb,
                                                const float* __restrict__ b1,
                                                float* __restrict__ part_q,
                                                float* __restrict__ part_k,
                                                float* __restrict__ sk) {
  __shared__ __align__(16) unsigned short As[128 * 64];
  __shared__ __align__(16) unsigned short Bs[128 * 64];
  __shared__ float red[8];
  const int p = blockIdx.x + (blockIdx.y << 7) + (blockIdx.z << 10);
  const int xc = p & 7, m = p >> 3;
  const int bxi = (xc << 4) | (m & 15);
  const int yi = (m >> 4) & 7;
  const int z = m >> 7;
  const int tid = threadIdx.x;
  const int wave = tid >> 6, lane = tid & 63;
  const int bm = bxi << 7;
  const int batch = bxi >> 5;
  const bool first = yi < 4;
  const int widx = z ? (first ? 1 : 2) : (first ? 0 : 3);
  const unsigned short* A = z ? akv16 : a16;
  const unsigned short* B = w16s + (size_t)262144 * ((widx << 2) | batch);
  const int bnl = (yi & 3) << 7;
  const int wr = (wave >> 1) << 6;
  const int wc = (wave & 1) << 6;
  const int lr = lane & 15, lg = lane >> 4;

  f32x4 acc[4][4] = {};
  const int srow = lane >> 3;
  const int sslot = (lane & 7) ^ srow;

  for (int k0 = 0; k0 < 512; k0 += 64) {
    __syncthreads();
#pragma unroll
    for (int i = 0; i < 4; ++i) {
      const int ci = wave * 4 + i;
      const int row = ci * 8 + srow;
      GLOAD16(A + (size_t)(bm + row) * 512 + k0 + sslot * 8, (char*)As + ci * 1024);
      GLOAD16(B + (size_t)(bnl + row) * 512 + k0 + sslot * 8, (char*)Bs + ci * 1024);
    }
    __syncthreads();
#pragma unroll
    for (int kk = 0; kk < 64; kk += 32) {
      bf16x8 af[4], bfr[4];
#pragma unroll
      for (int i = 0; i < 4; ++i) {
        const int row = wr + i * 16 + lr;
        af[i] = *(const bf16x8*)&As[row * 64 + ((((kk >> 3) + lg) ^ (row & 7)) << 3)];
      }
#pragma unroll
      for (int j = 0; j < 4; ++j) {
        const int row = wc + j * 16 + lr;
        bfr[j] = *(const bf16x8*)&Bs[row * 64 + ((((kk >> 3) + lg) ^ (row & 7)) << 3)];
      }
#pragma unroll
      for (int i = 0; i < 4; ++i)
#pragma unroll
        for (int j = 0; j < 4; ++j)
          acc[i][j] = __builtin_amdgcn_mfma_f32_16x16x32_bf16(af[i], bfr[j], acc[i][j], 0, 0, 0);
    }
  }

  {
    const float* cb = corr + (((widx << 2) | batch) << 9);
    float cj[4];
#pragma unroll
    for (int j = 0; j < 4; ++j) cj[j] = cb[bnl + wc + j * 16 + lr];
#pragma unroll
    for (int i = 0; i < 4; ++i)
#pragma unroll
      for (int j = 0; j < 4; ++j)
#pragma unroll
        for (int r = 0; r < 4; ++r) acc[i][j][r] -= cj[j];
  }

  if (first) {
    unsigned short* C0 = z ? k16 : q16;
#pragma unroll
    for (int i = 0; i < 4; ++i) {
      const int row0 = bm + wr + i * 16 + lg * 4;
#pragma unroll
      for (int j = 0; j < 4; ++j) {
        const int col = bnl + wc + j * 16 + lr;
#pragma unroll
        for (int r = 0; r < 4; ++r)
          C0[(size_t)(row0 + r) * 512 + col] = f2b(acc[i][j][r]);
      }
    }
    float s = 0.f, sq = 0.f;
#pragma unroll
    for (int i = 0; i < 4; ++i)
#pragma unroll
      for (int j = 0; j < 4; ++j)
#pragma unroll
        for (int r = 0; r < 4; ++r) { const float v = acc[i][j][r]; s += v; sq += v * v; }
#pragma unroll
    for (int o = 32; o > 0; o >>= 1) { s += __shfl_xor(s, o); sq += __shfl_xor(sq, o); }
    if (lane == 0) { red[wave * 2] = s; red[wave * 2 + 1] = sq; }
    __syncthreads();
    if (tid == 0) {
      float* part = z ? part_k : part_q;
      const float S = red[0] + red[2] + red[4] + red[6];
      const float SQ = red[1] + red[3] + red[5] + red[7];
      const int slot = bxi & 31, g = yi;
      const int idx = ((((batch << 2) | g) << 5) | slot) << 1;
      part[idx] = S;
      part[idx + 1] = SQ;
    }
    if (z) {
      const int head = (bnl >> 6) + (wave & 1);
#pragma unroll
      for (int i = 0; i < 4; ++i) {
#pragma unroll
        for (int r = 0; r < 4; ++r) {
          float t = acc[i][0][r] + acc[i][1][r] + acc[i][2][r] + acc[i][3][r];
#pragma unroll
          for (int o = 1; o < 16; o <<= 1) t += __shfl_xor(t, o);
          if (lr == 0)
            sk[(size_t)(bm + wr + i * 16 + lg * 4 + r) * 8 + head] = t;
        }
      }
    }
  } else if (z == 0) {
#pragma unroll
    for (int i = 0; i < 4; ++i) {
      const int row0 = bm + wr + i * 16 + lg * 4;
#pragma unroll
      for (int j = 0; j < 4; ++j) {
        const int col = bnl + wc + j * 16 + lr;
        const float bb = b1[col];
#pragma unroll
        for (int r = 0; r < 4; ++r) {
          float v = acc[i][j][r] + bb;
          v = v > 0.f ? v : 0.01f * v;
          h16[(size_t)(row0 + r) * 512 + col] = f2b(v);
        }
      }
    }
  } else {
#pragma unroll
    for (int i = 0; i < 4; ++i) {
      const int row0 = bm + wr + i * 16 + lg * 4;
#pragma unroll
      for (int j = 0; j < 4; ++j) {
        const int col = bnl + wc + j * 16 + lr;
        us4 pk;
#pragma unroll
        for (int r = 0; r < 4; ++r) pk[r] = f2b(acc[i][j][r]);
        *(us4*)&vTb[((size_t)(row0 >> 9) * 512 + col) * 512 + (row0 & 511)] = pk;
      }
    }
  }
}

// -------- final GEMM (grid (128,4), XCD-swizzled): out = [ao|h1] @ [Wz|W2]^T + ... --------
__global__ __launch_bounds__(256) void gemm_final(const unsigned short* __restrict__ A0,
                                                  const unsigned short* __restrict__ A1,
                                                  const unsigned short* __restrict__ B0,
                                                  const unsigned short* __restrict__ B1,
                                                  float* __restrict__ Cf,
                                                  const float* __restrict__ bias0,
                                                  const float* __restrict__ bias1,
                                                  const unsigned short* __restrict__ init16) {
  __shared__ __align__(16) unsigned short As[128 * 64];
  __shared__ __align__(16) unsigned short Bs[128 * 64];
  const int p = blockIdx.x + (blockIdx.y << 7);
  const int xc = p & 7, m = p >> 3;
  const int bxi = (xc << 4) | (m & 15);
  const int bni = (m >> 4) & 3;
  const int tid = threadIdx.x;
  const int wave = tid >> 6, lane = tid & 63;
  const int bm = bxi << 7, bn = bni << 7;
  const int wr = (wave >> 1) << 6;
  const int wc = (wave & 1) << 6;
  const int lr = lane & 15, lg = lane >> 4;

  f32x4 acc[4][4] = {};
  const int srow = lane >> 3;
  const int sslot = (lane & 7) ^ srow;

  for (int k0 = 0; k0 < 1024; k0 += 64) {
    const unsigned short* Ab = (k0 < 512) ? A0 : A1;
    const unsigned short* Bb = (k0 < 512) ? B0 : B1;
    const int kl = k0 & 511;
    __syncthreads();
#pragma unroll
    for (int i = 0; i < 4; ++i) {
      const int ci = wave * 4 + i;
      const int row = ci * 8 + srow;
      GLOAD16(Ab + (size_t)(bm + row) * 512 + kl + sslot * 8, (char*)As + ci * 1024);
      GLOAD16(Bb + (size_t)(bn + row) * 512 + kl + sslot * 8, (char*)Bs + ci * 1024);
    }
    __syncthreads();
#pragma unroll
    for (int kk = 0; kk < 64; kk += 32) {
      bf16x8 af[4], bfr[4];
#pragma unroll
      for (int i = 0; i < 4; ++i) {
        const int row = wr + i * 16 + lr;
        af[i] = *(const bf16x8*)&As[row * 64 + ((((kk >> 3) + lg) ^ (row & 7)) << 3)];
      }
#pragma unroll
      for (int j = 0; j < 4; ++j) {
        const int row = wc + j * 16 + lr;
        bfr[j] = *(const bf16x8*)&Bs[row * 64 + ((((kk >> 3) + lg) ^ (row & 7)) << 3)];
      }
#pragma unroll
      for (int i = 0; i < 4; ++i)
#pragma unroll
        for (int j = 0; j < 4; ++j)
          acc[i][j] = __builtin_amdgcn_mfma_f32_16x16x32_bf16(af[i], bfr[j], acc[i][j], 0, 0, 0);
    }
  }

#pragma unroll
  for (int i = 0; i < 4; ++i) {
    const int row0 = bm + wr + i * 16 + lg * 4;
#pragma unroll
    for (int j = 0; j < 4; ++j) {
      const int col = bn + wc + j * 16 + lr;
      const float bb = bias0[col] + bias1[col];
#pragma unroll
      for (int r = 0; r < 4; ++r) {
        const size_t o = (size_t)(row0 + r) * 512 + col;
        Cf[o] = acc[i][j][r] + bb + b2f(init16[o]);
      }
    }
  }
}

// ------- fused attention: GN folded; LDS-transposed nt P-write; head-grouped dispatch ------
// grid 2048 1-D: xcd = p&7, seq = p>>3, head-id = xcd*32 + (seq>>3), q-tile = seq&7.
// The 8 q-tiles of one head run back-to-back on one XCD -> K/V L2-resident after tile 0.
__global__ __launch_bounds__(256) void attn_fused(const unsigned short* __restrict__ q16,
                                                  const unsigned short* __restrict__ k16,
                                                  const unsigned short* __restrict__ vT,
                                                  const float* __restrict__ part_q,
                                                  const float* __restrict__ part_k,
                                                  const float* __restrict__ sk,
                                                  float* __restrict__ aw,
                                                  unsigned short* __restrict__ ao16) {
  // manual union: [Qs 8KB | Ks 32KB | Ps 32KB] overlaid with Pf fp32[64][260] (66.5KB)
  __shared__ __align__(16) char smem[73728];
  unsigned short* Qs = (unsigned short*)smem;            // [64*64]
  unsigned short* Ks = (unsigned short*)(smem + 8192);   // [256*64] (K tiles; later V)
  unsigned short* Ps = (unsigned short*)(smem + 40960);  // [64*256]
  float* Pf = (float*)smem;                              // [64][260] staging for P-write
  __shared__ float WM[4][64];
  __shared__ float WS[4][64];
  __shared__ float sk_lds[512];
  __shared__ float cst[2];

  const int p = blockIdx.x;
  const int xcd = p & 7, seq = p >> 3;
  const int bid = (xcd << 5) | (seq >> 3);  // head-id 0..255
  const int q0 = (seq & 7) << 6;
  const int h = bid & 7;
  const int b = bid >> 6;
  const int tid = threadIdx.x;
  const int w = tid >> 6, lane = tid & 63;
  const int lr = lane & 15, lg = lane >> 4;
  const int srow = lane >> 3;
  const int sslot = (lane & 7) ^ srow;

  const size_t hb = (size_t)(bid >> 3) * (512 * 512);
  const unsigned short* Qg = q16 + hb + h * 64;
  const unsigned short* Kg = k16 + hb + h * 64;
  const unsigned short* Vg = vT + hb + (size_t)h * 64 * 512;

  if (tid == 0) {
    const int pbase = (((b << 2) | (h >> 1)) << 6);
    const float* pq = part_q + pbase;
    const float* pk = part_k + pbase;
    float Sq = 0.f, SQq = 0.f, Sk = 0.f, SQk = 0.f;
    for (int c = 0; c < 32; ++c) {
      Sq += pq[c * 2]; SQq += pq[c * 2 + 1];
      Sk += pk[c * 2]; SQk += pk[c * 2 + 1];
    }
    const float inv = 1.f / (float)(NTROWS * 128);
    const float muq = Sq * inv, vq = SQq * inv - muq * muq;
    const float muk = Sk * inv, vk = SQk * inv - muk * muk;
    const float a = rsqrtf(vq + EPSGN) * rsqrtf(vk + EPSGN) * 0.125f;
    cst[0] = a;
    cst[1] = a * muq;
  }
  {
    const float* skg = sk + (size_t)(bid >> 3) * 512 * 8 + h;
    for (int j = tid; j < 512; j += 256) sk_lds[j] = skg[(size_t)j * 8];
  }

#pragma unroll
  for (int it = 0; it < 2; ++it) {  // stage Q 64x64 async
    const int ci = w * 2 + it;
    const int row = ci * 8 + srow;
    GLOAD16(Qg + (size_t)(q0 + row) * 512 + sslot * 8, (char*)Qs + ci * 1024);
  }

  f32x4 sc[4][8] = {};

#pragma unroll
  for (int half = 0; half < 2; ++half) {
    __syncthreads();
#pragma unroll
    for (int it = 0; it < 8; ++it) {  // stage K half (per-wave region) async
      const int ci = w * 8 + it;
      const int row = ci * 8 + srow;
      GLOAD16(Kg + (size_t)(half * 256 + row) * 512 + sslot * 8, (char*)Ks + ci * 1024);
    }
    __syncthreads();
#pragma unroll
    for (int kk = 0; kk < 64; kk += 32) {
      bf16x8 aq[4];
#pragma unroll
      for (int qf = 0; qf < 4; ++qf) {
        const int row = qf * 16 + lr;
        aq[qf] = *(const bf16x8*)&Qs[row * 64 + ((((kk >> 3) + lg) ^ (row & 7)) << 3)];
      }
#pragma unroll
      for (int kf = 0; kf < 4; ++kf) {
        const int row = w * 64 + kf * 16 + lr;
        const bf16x8 bk = *(const bf16x8*)&Ks[row * 64 + ((((kk >> 3) + lg) ^ (row & 7)) << 3)];
#pragma unroll
        for (int qf = 0; qf < 4; ++qf)
          sc[qf][half * 4 + kf] =
              __builtin_amdgcn_mfma_f32_16x16x32_bf16(aq[qf], bk, sc[qf][half * 4 + kf], 0, 0, 0);
      }
    }
  }

  // ---- GN correction: logit = a*S - a*mu_q*Sk[col] ----
  const float aSc = cst[0], cmu = cst[1];
#pragma unroll
  for (int qf = 0; qf < 4; ++qf)
#pragma unroll
    for (int kfi = 0; kfi < 8; ++kfi) {
      const int k = ((kfi >> 2) << 8) + w * 64 + ((kfi & 3) << 4) + lr;
      const float corr = cmu * sk_lds[k];
#pragma unroll
      for (int r = 0; r < 4; ++r) sc[qf][kfi][r] = aSc * sc[qf][kfi][r] - corr;
    }

  // ---- softmax ----
  float Mv[4][4];
#pragma unroll
  for (int qf = 0; qf < 4; ++qf)
#pragma unroll
    for (int r = 0; r < 4; ++r) {
      float m = sc[qf][0][r];
#pragma unroll
      for (int kf = 1; kf < 8; ++kf) m = fmaxf(m, sc[qf][kf][r]);
#pragma unroll
      for (int o = 1; o < 16; o <<= 1) m = fmaxf(m, __shfl_xor(m, o));
      Mv[qf][r] = m;
    }
  if (lr == 0) {
#pragma unroll
    for (int qf = 0; qf < 4; ++qf)
#pragma unroll
      for (int r = 0; r < 4; ++r) WM[w][qf * 16 + lg * 4 + r] = Mv[qf][r];
  }
  __syncthreads();
#pragma unroll
  for (int qf = 0; qf < 4; ++qf)
#pragma unroll
    for (int r = 0; r < 4; ++r) {
      const int q = qf * 16 + lg * 4 + r;
      Mv[qf][r] = fmaxf(fmaxf(WM[0][q], WM[1][q]), fmaxf(WM[2][q], WM[3][q]));
    }
  float sl[4][4] = {};
#pragma unroll
  for (int qf = 0; qf < 4; ++qf)
#pragma unroll
    for (int kf = 0; kf < 8; ++kf) {
      f32x4 v = sc[qf][kf];
#pragma unroll
      for (int r = 0; r < 4; ++r) {
        const float e = __expf(v[r] - Mv[qf][r]);
        v[r] = e;
        sl[qf][r] += e;
      }
      sc[qf][kf] = v;
    }
#pragma unroll
  for (int qf = 0; qf < 4; ++qf)
#pragma unroll
    for (int r = 0; r < 4; ++r) {
      float s = sl[qf][r];
#pragma unroll
      for (int o = 1; o < 16; o <<= 1) s += __shfl_xor(s, o);
      sl[qf][r] = s;
    }
  if (lr == 0) {
#pragma unroll
    for (int qf = 0; qf < 4; ++qf)
#pragma unroll
      for (int r = 0; r < 4; ++r) WS[w][qf * 16 + lg * 4 + r] = sl[qf][r];
  }
  __syncthreads();
#pragma unroll
  for (int qf = 0; qf < 4; ++qf)
#pragma unroll
    for (int r = 0; r < 4; ++r) {
      const int q = qf * 16 + lg * 4 + r;
      const float inv = 1.f / (WS[0][q] + WS[1][q] + WS[2][q] + WS[3][q]);
#pragma unroll
      for (int kf = 0; kf < 8; ++kf) sc[qf][kf][r] *= inv;
    }

  // ---- P-write via LDS transpose: coalesced 16B/lane nontemporal stores ----
  float* AWp = aw + ((size_t)bid * 512 + q0) * 512;
#pragma unroll
  for (int half = 0; half < 2; ++half) {
#pragma unroll
    for (int qf = 0; qf < 4; ++qf)
#pragma unroll
      for (int s2 = 0; s2 < 4; ++s2) {
        const int kl = w * 64 + (s2 << 4) + lr;
#pragma unroll
        for (int r = 0; r < 4; ++r) {
          const int q = qf * 16 + lg * 4 + r;
          Pf[q * 260 + kl] = sc[qf][half * 4 + s2][r];
        }
      }
    __syncthreads();
#pragma unroll
    for (int rr = 0; rr < 16; ++rr) {
      const int q = w * 16 + rr;
      const f32x4 v = *(const f32x4*)&Pf[q * 260 + lane * 4];
      __builtin_nontemporal_store(
          v, (f32x4*)&AWp[(size_t)q * 512 + half * 256 + lane * 4]);
    }
    __syncthreads();
  }

  // ---- PV: V half0 + Ps half0 ----
#pragma unroll
  for (int it = 0; it < 8; ++it) {
    const int ci = w * 8 + it;
    const int row = ci * 2 + (lane >> 5);
    const int s = lane & 31;
    GLOAD16(Vg + (size_t)row * 512 + ((s ^ (row & 7)) << 3), (char*)Ks + ci * 1024);
  }
#pragma unroll
  for (int qf = 0; qf < 4; ++qf)
#pragma unroll
    for (int r = 0; r < 4; ++r) {
      const int q = qf * 16 + lg * 4 + r;
#pragma unroll
      for (int kf = 0; kf < 4; ++kf) {
        const int k = w * 64 + (kf << 4) + lr;
        Ps[q * 256 + (((k >> 3) ^ (q & 7)) << 3) + (k & 7)] = f2b(sc[qf][kf][r]);
      }
    }
  __syncthreads();

  f32x4 accO[4] = {};
#pragma unroll
  for (int ks = 0; ks < 256; ks += 32) {
    const int sl0 = ks >> 3;
    const int q = w * 16 + lr;
    const bf16x8 af = *(const bf16x8*)&Ps[q * 256 + (((sl0 + lg) ^ (q & 7)) << 3)];
#pragma unroll
    for (int df = 0; df < 4; ++df) {
      const int row = df * 16 + lr;
      const bf16x8 vb = *(const bf16x8*)&Ks[row * 256 + (((sl0 + lg) ^ (row & 7)) << 3)];
      accO[df] = __builtin_amdgcn_mfma_f32_16x16x32_bf16(af, vb, accO[df], 0, 0, 0);
    }
  }
  __syncthreads();

  // V half1 + Ps half1
#pragma unroll
  for (int it = 0; it < 8; ++it) {
    const int ci = w * 8 + it;
    const int row = ci * 2 + (lane >> 5);
    const int s = lane & 31;
    GLOAD16(Vg + (size_t)row * 512 + 256 + ((s ^ (row & 7)) << 3), (char*)Ks + ci * 1024);
  }
#pragma unroll
  for (int qf = 0; qf < 4; ++qf)
#pragma unroll
    for (int r = 0; r < 4; ++r) {
      const int q = qf * 16 + lg * 4 + r;
#pragma unroll
      for (int kf = 0; kf < 4; ++kf) {
        const int k = w * 64 + (kf << 4) + lr;
        Ps[q * 256 + (((k >> 3) ^ (q & 7)) << 3) + (k & 7)] = f2b(sc[qf][4 + kf][r]);
      }
    }
  __syncthreads();

#pragma unroll
  for (int ks = 0; ks < 256; ks += 32) {
    const int sl0 = ks >> 3;
    const int q = w * 16 + lr;
    const bf16x8 af = *(const bf16x8*)&Ps[q * 256 + (((sl0 + lg) ^ (q & 7)) << 3)];
#pragma unroll
    for (int df = 0; df < 4; ++df) {
      const int row = df * 16 + lr;
      const bf16x8 vb = *(const bf16x8*)&Ks[row * 256 + (((sl0 + lg) ^ (row & 7)) << 3)];
      accO[df] = __builtin_amdgcn_mfma_f32_16x16x32_bf16(af, vb, accO[df], 0, 0, 0);
    }
  }

  const int growb = (bid >> 3) * 512 + q0 + w * 16 + lg * 4;
#pragma unroll
  for (int df = 0; df < 4; ++df)
#pragma unroll
    for (int r = 0; r < 4; ++r)
      ao16[(size_t)(growb + r) * 512 + h * 64 + df * 16 + lr] = f2b(accO[df][r]);
}

// ---------------- launcher ----------------
extern "C" void kernel_launch(void* const* d_in, const int* in_sizes, int n_in,
                              void* d_out, int out_size, void* d_ws, size_t ws_size,
                              hipStream_t stream) {
  const float* in_f = (const float*)d_in[1];
  const float* in_fkv = (const float*)d_in[2];
  const float* Wq = (const float*)d_in[3];
  const float* Wk = (const float*)d_in[4];
  const float* Wv = (const float*)d_in[5];
  const float* Wz = (const float*)d_in[6];
  const float* bz = (const float*)d_in[7];
  const float* W1 = (const float*)d_in[8];
  const float* b1 = (const float*)d_in[9];
  const float* W2 = (const float*)d_in[10];
  const float* b2 = (const float*)d_in[11];

  float* out_f = (float*)d_out;
  float* attw = out_f + (size_t)MROWS * DDIM;

  const size_t TSB = (size_t)MROWS * DDIM;
  unsigned short* us = (unsigned short*)d_ws;
  unsigned short* a16 = us;
  unsigned short* akv16 = us + TSB;
  unsigned short* q16 = us + 2 * TSB;
  unsigned short* k16 = us + 3 * TSB;
  unsigned short* h16 = us + 4 * TSB;
  unsigned short* ao16 = us + 5 * TSB;
  unsigned short* vT = us + 6 * TSB;
  unsigned short* w16s = us + 7 * TSB;
  float* fbase = (float*)(us + 7 * TSB + 18 * 262144);
  float* p0 = fbase;
  float* p1 = fbase + 4096;
  float* part_q = fbase + 8192;
  float* part_k = fbase + 9216;
  float* corr = fbase + 10240;
  float* sk = fbase + 18432;

  stats_cvt<<<dim3(512, 3), 256, 0, stream>>>(in_f, in_fkv, a16, akv16, p0, p1, Wz, W2, w16s);
  wprep<<<dim3(128, 16), 256, 0, stream>>>(Wq, Wk, Wv, W1, p0, p1, w16s, corr);
  gemm_all<<<dim3(128, 8, 2), 256, 0, stream>>>(a16, akv16, w16s, corr, q16, h16, k16, vT, b1,
                                                part_q, part_k, sk);
  attn_fused<<<2048, 256, 0, stream>>>(q16, k16, vT, part_q, part_k, sk, attw, ao16);
  gemm_final<<<dim3(128, 4), 256, 0, stream>>>(ao16, h16, w16s + 16 * 262144,
                                               w16s + 17 * 262144, out_f, bz, b2, a16);
}

// Round 16
// 230.049 us; speedup vs baseline: 1.2130x; 1.0005x over previous
//
#include <hip/hip_runtime.h>
#include <math.h>

#define TDIM 512
#define DDIM 512
#define NTROWS 4096
#define MROWS 16384
#define EPSGN 1e-3f

typedef __attribute__((ext_vector_type(8))) short bf16x8;
typedef __attribute__((ext_vector_type(4))) float f32x4;
typedef __attribute__((ext_vector_type(8))) unsigned short us8;
typedef __attribute__((ext_vector_type(4))) unsigned short us4;

__device__ __forceinline__ unsigned short f2b(float f) {
  unsigned int u = __float_as_uint(f);
  return (unsigned short)((u + 0x7fffu + ((u >> 16) & 1u)) >> 16);
}
__device__ __forceinline__ float b2f(unsigned short h) {
  return __uint_as_float(((unsigned int)h) << 16);
}

#define GLOAD16(g, l)                                                                   \
  __builtin_amdgcn_global_load_lds((const __attribute__((address_space(1))) void*)(g),  \
                                   (__attribute__((address_space(3))) void*)(l), 16, 0, 0)

// ------- fused: fp32 -> raw bf16 convert + GroupNorm partial stats (+ Wz/W2 convert) -------
__global__ __launch_bounds__(256) void stats_cvt(const float* __restrict__ x0,
                                                 const float* __restrict__ x1,
                                                 unsigned short* __restrict__ o0,
                                                 unsigned short* __restrict__ o1,
                                                 float* __restrict__ p0,
                                                 float* __restrict__ p1,
                                                 const float* __restrict__ Wz,
                                                 const float* __restrict__ W2,
                                                 unsigned short* __restrict__ w16s) {
  if (blockIdx.y == 2) {
    const int bid = blockIdx.x;
    if (bid >= 256) return;
    const int c = bid * 256 + threadIdx.x;
    const int t = c >> 15;
    const int off = c & 32767;
    const float* s = t ? W2 : Wz;
    unsigned short* d = w16s + (size_t)(16 + t) * 262144;
    const float4 f0 = *(const float4*)(s + (size_t)off * 8);
    const float4 f1 = *(const float4*)(s + (size_t)off * 8 + 4);
    us8 v;
    v[0] = f2b(f0.x); v[1] = f2b(f0.y); v[2] = f2b(f0.z); v[3] = f2b(f0.w);
    v[4] = f2b(f1.x); v[5] = f2b(f1.y); v[6] = f2b(f1.z); v[7] = f2b(f1.w);
    *(us8*)(d + (size_t)off * 8) = v;
    return;
  }
  const float* x = blockIdx.y ? x1 : x0;
  unsigned short* o = blockIdx.y ? o1 : o0;
  float* part = blockIdx.y ? p1 : p0;
  const int blk = blockIdx.x;
  const int batch = blk >> 7;
  const int chunk = blk & 127;
  const size_t base = (size_t)blk * 32 * 512;
  const int tid = threadIdx.x;
  float s = 0.f, sq = 0.f;
#pragma unroll 4
  for (int it = 0; it < 8; ++it) {
    const size_t e = base + (size_t)it * 2048 + (size_t)tid * 8;
    const float4 f0 = *(const float4*)(x + e);
    const float4 f1 = *(const float4*)(x + e + 4);
    us8 v;
    v[0] = f2b(f0.x); v[1] = f2b(f0.y); v[2] = f2b(f0.z); v[3] = f2b(f0.w);
    v[4] = f2b(f1.x); v[5] = f2b(f1.y); v[6] = f2b(f1.z); v[7] = f2b(f1.w);
    *(us8*)(o + e) = v;
    s += f0.x + f0.y + f0.z + f0.w + f1.x + f1.y + f1.z + f1.w;
    sq += f0.x * f0.x + f0.y * f0.y + f0.z * f0.z + f0.w * f0.w +
          f1.x * f1.x + f1.y * f1.y + f1.z * f1.z + f1.w * f1.w;
  }
  const int wave = tid >> 6, lane = tid & 63;
#pragma unroll
  for (int of = 1; of < 16; of <<= 1) { s += __shfl_xor(s, of); sq += __shfl_xor(sq, of); }
  __shared__ float red[4][4][2];
  if ((lane & 15) == 0) { red[wave][lane >> 4][0] = s; red[wave][lane >> 4][1] = sq; }
  __syncthreads();
  if (tid < 4) {
    float S = 0.f, SQ = 0.f;
#pragma unroll
    for (int w = 0; w < 4; ++w) { S += red[w][tid][0]; SQ += red[w][tid][1]; }
    const int idx = (((batch << 2) | tid) << 7) | chunk;
    part[idx * 2] = S;
    part[idx * 2 + 1] = SQ;
  }
}

// ---------------- weight prep: per-batch GN-scaled weights + column corrections ------------
__global__ __launch_bounds__(256) void wprep(const float* __restrict__ Wq,
                                             const float* __restrict__ Wk,
                                             const float* __restrict__ Wv,
                                             const float* __restrict__ W1,
                                             const float* __restrict__ p0,
                                             const float* __restrict__ p1,
                                             unsigned short* __restrict__ w16s,
                                             float* __restrict__ corr) {
  const int y = blockIdx.y;
  const int w = y >> 2, b = y & 3;
  const float* W = (w == 0) ? Wq : (w == 1) ? Wk : (w == 2) ? Wv : W1;
  const float* part = (w == 0 || w == 3) ? p0 : p1;
  __shared__ float mrs[4][2];
  if (threadIdx.x < 4) {
    const float* p = part + (((b << 2) | threadIdx.x) << 7) * 2;
    float S = 0.f, SQ = 0.f;
    for (int c = 0; c < 128; ++c) { S += p[c * 2]; SQ += p[c * 2 + 1]; }
    const float inv = 1.f / (float)(NTROWS * 128);
    const float mu = S * inv;
    const float var = SQ * inv - mu * mu;
    const float rs = rsqrtf(var + EPSGN);
    mrs[threadIdx.x][0] = rs;
    mrs[threadIdx.x][1] = mu * rs;
  }
  __syncthreads();
  const int wave = threadIdx.x >> 6, lane = threadIdx.x & 63;
  const int n = blockIdx.x * 4 + wave;
  const int k = lane * 8;
  const int g = lane >> 4;
  const float rs = mrs[g][0], murs = mrs[g][1];
  const float4 f0 = *(const float4*)(W + (size_t)n * 512 + k);
  const float4 f1 = *(const float4*)(W + (size_t)n * 512 + k + 4);
  us8 v;
  v[0] = f2b(f0.x * rs); v[1] = f2b(f0.y * rs); v[2] = f2b(f0.z * rs); v[3] = f2b(f0.w * rs);
  v[4] = f2b(f1.x * rs); v[5] = f2b(f1.y * rs); v[6] = f2b(f1.z * rs); v[7] = f2b(f1.w * rs);
  *(us8*)(w16s + (size_t)((w << 2) | b) * 262144 + (size_t)n * 512 + k) = v;
  float t = (f0.x + f0.y + f0.z + f0.w + f1.x + f1.y + f1.z + f1.w) * murs;
#pragma unroll
  for (int of = 1; of < 64; of <<= 1) t += __shfl_xor(t, of);
  if (lane == 0) corr[(((w << 2) | b) << 9) | n] = t;
}

// ---------------- unified projection GEMMs (grid (128,8,2), XCD-swizzled) ----------------
__global__ __launch_bounds__(256) void gemm_all(const unsigned short* __restrict__ a16,
                                                const unsigned short* __restrict__ akv16,
                                                const unsigned short* __restrict__ w16s,
                                                const float* __restrict__ corr,
                                                unsigned short* __restrict__ q16,
                                                unsigned short* __restrict__ h16,
                                                unsigned short* __restrict__ k16,
                                                unsigned short* __restrict__ vTb,
                                                const float* __restrict__ b1,
                                                float* __restrict__ part_q,
                                                float* __restrict__ part_k,
                                                float* __restrict__ sk) {
  __shared__ __align__(16) unsigned short As[128 * 64];
  __shared__ __align__(16) unsigned short Bs[128 * 64];
  __shared__ float red[8];
  const int p = blockIdx.x + (blockIdx.y << 7) + (blockIdx.z << 10);
  const int xc = p & 7, m = p >> 3;
  const int bxi = (xc << 4) | (m & 15);
  const int yi = (m >> 4) & 7;
  const int z = m >> 7;
  const int tid = threadIdx.x;
  const int wave = tid >> 6, lane = tid & 63;
  const int bm = bxi << 7;
  const int batch = bxi >> 5;
  const bool first = yi < 4;
  const int widx = z ? (first ? 1 : 2) : (first ? 0 : 3);
  const unsigned short* A = z ? akv16 : a16;
  const unsigned short* B = w16s + (size_t)262144 * ((widx << 2) | batch);
  const int bnl = (yi & 3) << 7;
  const int wr = (wave >> 1) << 6;
  const int wc = (wave & 1) << 6;
  const int lr = lane & 15, lg = lane >> 4;

  f32x4 acc[4][4] = {};
  const int srow = lane >> 3;
  const int sslot = (lane & 7) ^ srow;

  for (int k0 = 0; k0 < 512; k0 += 64) {
    __syncthreads();
#pragma unroll
    for (int i = 0; i < 4; ++i) {
      const int ci = wave * 4 + i;
      const int row = ci * 8 + srow;
      GLOAD16(A + (size_t)(bm + row) * 512 + k0 + sslot * 8, (char*)As + ci * 1024);
      GLOAD16(B + (size_t)(bnl + row) * 512 + k0 + sslot * 8, (char*)Bs + ci * 1024);
    }
    __syncthreads();
#pragma unroll
    for (int kk = 0; kk < 64; kk += 32) {
      bf16x8 af[4], bfr[4];
#pragma unroll
      for (int i = 0; i < 4; ++i) {
        const int row = wr + i * 16 + lr;
        af[i] = *(const bf16x8*)&As[row * 64 + ((((kk >> 3) + lg) ^ (row & 7)) << 3)];
      }
#pragma unroll
      for (int j = 0; j < 4; ++j) {
        const int row = wc + j * 16 + lr;
        bfr[j] = *(const bf16x8*)&Bs[row * 64 + ((((kk >> 3) + lg) ^ (row & 7)) << 3)];
      }
#pragma unroll
      for (int i = 0; i < 4; ++i)
#pragma unroll
        for (int j = 0; j < 4; ++j)
          acc[i][j] = __builtin_amdgcn_mfma_f32_16x16x32_bf16(af[i], bfr[j], acc[i][j], 0, 0, 0);
    }
  }

  {
    const float* cb = corr + (((widx << 2) | batch) << 9);
    float cj[4];
#pragma unroll
    for (int j = 0; j < 4; ++j) cj[j] = cb[bnl + wc + j * 16 + lr];
#pragma unroll
    for (int i = 0; i < 4; ++i)
#pragma unroll
      for (int j = 0; j < 4; ++j)
#pragma unroll
        for (int r = 0; r < 4; ++r) acc[i][j][r] -= cj[j];
  }

  if (first) {
    unsigned short* C0 = z ? k16 : q16;
#pragma unroll
    for (int i = 0; i < 4; ++i) {
      const int row0 = bm + wr + i * 16 + lg * 4;
#pragma unroll
      for (int j = 0; j < 4; ++j) {
        const int col = bnl + wc + j * 16 + lr;
#pragma unroll
        for (int r = 0; r < 4; ++r)
          C0[(size_t)(row0 + r) * 512 + col] = f2b(acc[i][j][r]);
      }
    }
    float s = 0.f, sq = 0.f;
#pragma unroll
    for (int i = 0; i < 4; ++i)
#pragma unroll
      for (int j = 0; j < 4; ++j)
#pragma unroll
        for (int r = 0; r < 4; ++r) { const float v = acc[i][j][r]; s += v; sq += v * v; }
#pragma unroll
    for (int o = 32; o > 0; o >>= 1) { s += __shfl_xor(s, o); sq += __shfl_xor(sq, o); }
    if (lane == 0) { red[wave * 2] = s; red[wave * 2 + 1] = sq; }
    __syncthreads();
    if (tid == 0) {
      float* part = z ? part_k : part_q;
      const float S = red[0] + red[2] + red[4] + red[6];
      const float SQ = red[1] + red[3] + red[5] + red[7];
      const int slot = bxi & 31, g = yi;
      const int idx = ((((batch << 2) | g) << 5) | slot) << 1;
      part[idx] = S;
      part[idx + 1] = SQ;
    }
    if (z) {
      const int head = (bnl >> 6) + (wave & 1);
#pragma unroll
      for (int i = 0; i < 4; ++i) {
#pragma unroll
        for (int r = 0; r < 4; ++r) {
          float t = acc[i][0][r] + acc[i][1][r] + acc[i][2][r] + acc[i][3][r];
#pragma unroll
          for (int o = 1; o < 16; o <<= 1) t += __shfl_xor(t, o);
          if (lr == 0)
            sk[(size_t)(bm + wr + i * 16 + lg * 4 + r) * 8 + head] = t;
        }
      }
    }
  } else if (z == 0) {
#pragma unroll
    for (int i = 0; i < 4; ++i) {
      const int row0 = bm + wr + i * 16 + lg * 4;
#pragma unroll
      for (int j = 0; j < 4; ++j) {
        const int col = bnl + wc + j * 16 + lr;
        const float bb = b1[col];
#pragma unroll
        for (int r = 0; r < 4; ++r) {
          float v = acc[i][j][r] + bb;
          v = v > 0.f ? v : 0.01f * v;
          h16[(size_t)(row0 + r) * 512 + col] = f2b(v);
        }
      }
    }
  } else {
#pragma unroll
    for (int i = 0; i < 4; ++i) {
      const int row0 = bm + wr + i * 16 + lg * 4;
#pragma unroll
      for (int j = 0; j < 4; ++j) {
        const int col = bnl + wc + j * 16 + lr;
        us4 pk;
#pragma unroll
        for (int r = 0; r < 4; ++r) pk[r] = f2b(acc[i][j][r]);
        *(us4*)&vTb[((size_t)(row0 >> 9) * 512 + col) * 512 + (row0 & 511)] = pk;
      }
    }
  }
}

// -------- final GEMM (grid (128,4), XCD-swizzled): out = [ao|h1] @ [Wz|W2]^T + ... --------
__global__ __launch_bounds__(256) void gemm_final(const unsigned short* __restrict__ A0,
                                                  const unsigned short* __restrict__ A1,
                                                  const unsigned short* __restrict__ B0,
                                                  const unsigned short* __restrict__ B1,
                                                  float* __restrict__ Cf,
                                                  const float* __restrict__ bias0,
                                                  const float* __restrict__ bias1,
                                                  const unsigned short* __restrict__ init16) {
  __shared__ __align__(16) unsigned short As[128 * 64];
  __shared__ __align__(16) unsigned short Bs[128 * 64];
  const int p = blockIdx.x + (blockIdx.y << 7);
  const int xc = p & 7, m = p >> 3;
  const int bxi = (xc << 4) | (m & 15);
  const int bni = (m >> 4) & 3;
  const int tid = threadIdx.x;
  const int wave = tid >> 6, lane = tid & 63;
  const int bm = bxi << 7, bn = bni << 7;
  const int wr = (wave >> 1) << 6;
  const int wc = (wave & 1) << 6;
  const int lr = lane & 15, lg = lane >> 4;

  f32x4 acc[4][4] = {};
  const int srow = lane >> 3;
  const int sslot = (lane & 7) ^ srow;

  for (int k0 = 0; k0 < 1024; k0 += 64) {
    const unsigned short* Ab = (k0 < 512) ? A0 : A1;
    const unsigned short* Bb = (k0 < 512) ? B0 : B1;
    const int kl = k0 & 511;
    __syncthreads();
#pragma unroll
    for (int i = 0; i < 4; ++i) {
      const int ci = wave * 4 + i;
      const int row = ci * 8 + srow;
      GLOAD16(Ab + (size_t)(bm + row) * 512 + kl + sslot * 8, (char*)As + ci * 1024);
      GLOAD16(Bb + (size_t)(bn + row) * 512 + kl + sslot * 8, (char*)Bs + ci * 1024);
    }
    __syncthreads();
#pragma unroll
    for (int kk = 0; kk < 64; kk += 32) {
      bf16x8 af[4], bfr[4];
#pragma unroll
      for (int i = 0; i < 4; ++i) {
        const int row = wr + i * 16 + lr;
        af[i] = *(const bf16x8*)&As[row * 64 + ((((kk >> 3) + lg) ^ (row & 7)) << 3)];
      }
#pragma unroll
      for (int j = 0; j < 4; ++j) {
        const int row = wc + j * 16 + lr;
        bfr[j] = *(const bf16x8*)&Bs[row * 64 + ((((kk >> 3) + lg) ^ (row & 7)) << 3)];
      }
#pragma unroll
      for (int i = 0; i < 4; ++i)
#pragma unroll
        for (int j = 0; j < 4; ++j)
          acc[i][j] = __builtin_amdgcn_mfma_f32_16x16x32_bf16(af[i], bfr[j], acc[i][j], 0, 0, 0);
    }
  }

#pragma unroll
  for (int i = 0; i < 4; ++i) {
    const int row0 = bm + wr + i * 16 + lg * 4;
#pragma unroll
    for (int j = 0; j < 4; ++j) {
      const int col = bn + wc + j * 16 + lr;
      const float bb = bias0[col] + bias1[col];
#pragma unroll
      for (int r = 0; r < 4; ++r) {
        const size_t o = (size_t)(row0 + r) * 512 + col;
        Cf[o] = acc[i][j][r] + bb + b2f(init16[o]);
      }
    }
  }
}

// ------- fused attention: head-grouped dispatch; V-half0 prefetch overlaps P-flush -------
// grid 2048 1-D: xcd = p&7, seq = p>>3, head-id = xcd*32 + (seq>>3), q-tile = seq&7.
// PV buffer roles: V lives in PsV (free during Pf flush), bf16 P in KsP (free after flush).
// P slot kfi = half*4+s2 -> column half*256 + w*64 + s2*16 + lr.
// Flush chunk c (cols [c*128,(c+1)*128) of P): half=c>>1; waves with (w>>1)==(c&1) stage
// all s2 at kl = (w&1)*64 + s2*16 + lr.
__global__ __launch_bounds__(256) void attn_fused(const unsigned short* __restrict__ q16,
                                                  const unsigned short* __restrict__ k16,
                                                  const unsigned short* __restrict__ vT,
                                                  const float* __restrict__ part_q,
                                                  const float* __restrict__ part_k,
                                                  const float* __restrict__ sk,
                                                  float* __restrict__ aw,
                                                  unsigned short* __restrict__ ao16) {
  __shared__ __align__(16) char smem[73728];
  unsigned short* Qs = (unsigned short*)smem;             // [64*64]
  unsigned short* KsP = (unsigned short*)(smem + 8192);   // K tiles (QK); bf16 P (PV)
  unsigned short* PsV = (unsigned short*)(smem + 40960);  // V tiles [64d][256k] (PV)
  float* Pf = (float*)smem;                               // [64][136] fp32 flush staging (34816B <= 40960B)
  __shared__ float WM[4][64];
  __shared__ float WS[4][64];
  __shared__ float sk_lds[512];
  __shared__ float cst[2];

  const int p = blockIdx.x;
  const int xcd = p & 7, seq = p >> 3;
  const int bid = (xcd << 5) | (seq >> 3);
  const int q0 = (seq & 7) << 6;
  const int h = bid & 7;
  const int b = bid >> 6;
  const int tid = threadIdx.x;
  const int w = tid >> 6, lane = tid & 63;
  const int lr = lane & 15, lg = lane >> 4;
  const int srow = lane >> 3;
  const int sslot = (lane & 7) ^ srow;

  const size_t hb = (size_t)(bid >> 3) * (512 * 512);
  const unsigned short* Qg = q16 + hb + h * 64;
  const unsigned short* Kg = k16 + hb + h * 64;
  const unsigned short* Vg = vT + hb + (size_t)h * 64 * 512;

  if (tid == 0) {
    const int pbase = (((b << 2) | (h >> 1)) << 6);
    const float* pq = part_q + pbase;
    const float* pk = part_k + pbase;
    float Sq = 0.f, SQq = 0.f, Sk = 0.f, SQk = 0.f;
    for (int c = 0; c < 32; ++c) {
      Sq += pq[c * 2]; SQq += pq[c * 2 + 1];
      Sk += pk[c * 2]; SQk += pk[c * 2 + 1];
    }
    const float inv = 1.f / (float)(NTROWS * 128);
    const float muq = Sq * inv, vq = SQq * inv - muq * muq;
    const float muk = Sk * inv, vk = SQk * inv - muk * muk;
    const float a = rsqrtf(vq + EPSGN) * rsqrtf(vk + EPSGN) * 0.125f;
    cst[0] = a;
    cst[1] = a * muq;
  }
  {
    const float* skg = sk + (size_t)(bid >> 3) * 512 * 8 + h;
    for (int j = tid; j < 512; j += 256) sk_lds[j] = skg[(size_t)j * 8];
  }

#pragma unroll
  for (int it = 0; it < 2; ++it) {  // stage Q 64x64 async
    const int ci = w * 2 + it;
    const int row = ci * 8 + srow;
    GLOAD16(Qg + (size_t)(q0 + row) * 512 + sslot * 8, (char*)Qs + ci * 1024);
  }

  f32x4 sc[4][8] = {};

#pragma unroll
  for (int half = 0; half < 2; ++half) {
    __syncthreads();
#pragma unroll
    for (int it = 0; it < 8; ++it) {  // stage K half (per-wave region) async
      const int ci = w * 8 + it;
      const int row = ci * 8 + srow;
      GLOAD16(Kg + (size_t)(half * 256 + row) * 512 + sslot * 8, (char*)KsP + ci * 1024);
    }
    __syncthreads();
#pragma unroll
    for (int kk = 0; kk < 64; kk += 32) {
      bf16x8 aq[4];
#pragma unroll
      for (int qf = 0; qf < 4; ++qf) {
        const int row = qf * 16 + lr;
        aq[qf] = *(const bf16x8*)&Qs[row * 64 + ((((kk >> 3) + lg) ^ (row & 7)) << 3)];
      }
#pragma unroll
      for (int kf = 0; kf < 4; ++kf) {
        const int row = w * 64 + kf * 16 + lr;
        const bf16x8 bk = *(const bf16x8*)&KsP[row * 64 + ((((kk >> 3) + lg) ^ (row & 7)) << 3)];
#pragma unroll
        for (int qf = 0; qf < 4; ++qf)
          sc[qf][half * 4 + kf] =
              __builtin_amdgcn_mfma_f32_16x16x32_bf16(aq[qf], bk, sc[qf][half * 4 + kf], 0, 0, 0);
      }
    }
  }

  // issue V half0 into PsV NOW — disjoint from Pf (Qs+KsP) used by the flush below.
#pragma unroll
  for (int it = 0; it < 8; ++it) {
    const int ci = w * 8 + it;
    const int row = ci * 2 + (lane >> 5);
    const int s = lane & 31;
    GLOAD16(Vg + (size_t)row * 512 + ((s ^ (row & 7)) << 3), (char*)PsV + ci * 1024);
  }

  // ---- GN correction: logit = a*S - a*mu_q*Sk[col] ----
  const float aSc = cst[0], cmu = cst[1];
#pragma unroll
  for (int qf = 0; qf < 4; ++qf)
#pragma unroll
    for (int kfi = 0; kfi < 8; ++kfi) {
      const int k = ((kfi >> 2) << 8) + w * 64 + ((kfi & 3) << 4) + lr;
      const float corr = cmu * sk_lds[k];
#pragma unroll
      for (int r = 0; r < 4; ++r) sc[qf][kfi][r] = aSc * sc[qf][kfi][r] - corr;
    }

  // ---- softmax ----
  float Mv[4][4];
#pragma unroll
  for (int qf = 0; qf < 4; ++qf)
#pragma unroll
    for (int r = 0; r < 4; ++r) {
      float m = sc[qf][0][r];
#pragma unroll
      for (int kf = 1; kf < 8; ++kf) m = fmaxf(m, sc[qf][kf][r]);
#pragma unroll
      for (int o = 1; o < 16; o <<= 1) m = fmaxf(m, __shfl_xor(m, o));
      Mv[qf][r] = m;
    }
  if (lr == 0) {
#pragma unroll
    for (int qf = 0; qf < 4; ++qf)
#pragma unroll
      for (int r = 0; r < 4; ++r) WM[w][qf * 16 + lg * 4 + r] = Mv[qf][r];
  }
  __syncthreads();
#pragma unroll
  for (int qf = 0; qf < 4; ++qf)
#pragma unroll
    for (int r = 0; r < 4; ++r) {
      const int q = qf * 16 + lg * 4 + r;
      Mv[qf][r] = fmaxf(fmaxf(WM[0][q], WM[1][q]), fmaxf(WM[2][q], WM[3][q]));
    }
  float sl[4][4] = {};
#pragma unroll
  for (int qf = 0; qf < 4; ++qf)
#pragma unroll
    for (int kf = 0; kf < 8; ++kf) {
      f32x4 v = sc[qf][kf];
#pragma unroll
      for (int r = 0; r < 4; ++r) {
        const float e = __expf(v[r] - Mv[qf][r]);
        v[r] = e;
        sl[qf][r] += e;
      }
      sc[qf][kf] = v;
    }
#pragma unroll
  for (int qf = 0; qf < 4; ++qf)
#pragma unroll
    for (int r = 0; r < 4; ++r) {
      float s = sl[qf][r];
#pragma unroll
      for (int o = 1; o < 16; o <<= 1) s += __shfl_xor(s, o);
      sl[qf][r] = s;
    }
  if (lr == 0) {
#pragma unroll
    for (int qf = 0; qf < 4; ++qf)
#pragma unroll
      for (int r = 0; r < 4; ++r) WS[w][qf * 16 + lg * 4 + r] = sl[qf][r];
  }
  __syncthreads();
#pragma unroll
  for (int qf = 0; qf < 4; ++qf)
#pragma unroll
    for (int r = 0; r < 4; ++r) {
      const int q = qf * 16 + lg * 4 + r;
      const float inv = 1.f / (WS[0][q] + WS[1][q] + WS[2][q] + WS[3][q]);
#pragma unroll
      for (int kf = 0; kf < 8; ++kf) sc[qf][kf][r] *= inv;
    }

  // ---- P-write via LDS transpose in 128-col chunks (Pf fits Qs+KsP; PsV untouched) ----
  float* AWp = aw + ((size_t)bid * 512 + q0) * 512;
#pragma unroll
  for (int c = 0; c < 4; ++c) {
    const int half = c >> 1;
    if ((w >> 1) == (c & 1)) {  // this wave's columns fall in chunk c
      const int base_kl = (w & 1) << 6;
#pragma unroll
      for (int qf = 0; qf < 4; ++qf)
#pragma unroll
        for (int s2 = 0; s2 < 4; ++s2) {
          const int kl = base_kl + (s2 << 4) + lr;
#pragma unroll
          for (int r = 0; r < 4; ++r) {
            const int q = qf * 16 + lg * 4 + r;
            Pf[q * 136 + kl] = sc[qf][half * 4 + s2][r];
          }
        }
    }
    __syncthreads();
#pragma unroll
    for (int rr = 0; rr < 8; ++rr) {  // 2 rows/iter/wave: lanes 0-31 row A, 32-63 row B
      const int q = w * 16 + rr * 2 + (lane >> 5);
      const int col = (lane & 31) * 4;
      const f32x4 v = *(const f32x4*)&Pf[q * 136 + col];
      __builtin_nontemporal_store(
          v, (f32x4*)&AWp[(size_t)q * 512 + c * 128 + col]);
    }
    __syncthreads();
  }

  // ---- PV half0: stage bf16 P into KsP; V already in PsV (drained by flush barriers) ----
#pragma unroll
  for (int qf = 0; qf < 4; ++qf)
#pragma unroll
    for (int r = 0; r < 4; ++r) {
      const int q = qf * 16 + lg * 4 + r;
#pragma unroll
      for (int kf = 0; kf < 4; ++kf) {
        const int k = w * 64 + (kf << 4) + lr;
        KsP[q * 256 + (((k >> 3) ^ (q & 7)) << 3) + (k & 7)] = f2b(sc[qf][kf][r]);
      }
    }
  __syncthreads();

  f32x4 accO[4] = {};
#pragma unroll
  for (int ks = 0; ks < 256; ks += 32) {
    const int sl0 = ks >> 3;
    const int q = w * 16 + lr;
    const bf16x8 af = *(const bf16x8*)&KsP[q * 256 + (((sl0 + lg) ^ (q & 7)) << 3)];
#pragma unroll
    for (int df = 0; df < 4; ++df) {
      const int row = df * 16 + lr;
      const bf16x8 vb = *(const bf16x8*)&PsV[row * 256 + (((sl0 + lg) ^ (row & 7)) << 3)];
      accO[df] = __builtin_amdgcn_mfma_f32_16x16x32_bf16(af, vb, accO[df], 0, 0, 0);
    }
  }
  __syncthreads();

  // V half1 into PsV + bf16 P half1 into KsP
#pragma unroll
  for (int it = 0; it < 8; ++it) {
    const int ci = w * 8 + it;
    const int row = ci * 2 + (lane >> 5);
    const int s = lane & 31;
    GLOAD16(Vg + (size_t)row * 512 + 256 + ((s ^ (row & 7)) << 3), (char*)PsV + ci * 1024);
  }
#pragma unroll
  for (int qf = 0; qf < 4; ++qf)
#pragma unroll
    for (int r = 0; r < 4; ++r) {
      const int q = qf * 16 + lg * 4 + r;
#pragma unroll
      for (int kf = 0; kf < 4; ++kf) {
        const int k = w * 64 + (kf << 4) + lr;
        KsP[q * 256 + (((k >> 3) ^ (q & 7)) << 3) + (k & 7)] = f2b(sc[qf][4 + kf][r]);
      }
    }
  __syncthreads();

#pragma unroll
  for (int ks = 0; ks < 256; ks += 32) {
    const int sl0 = ks >> 3;
    const int q = w * 16 + lr;
    const bf16x8 af = *(const bf16x8*)&KsP[q * 256 + (((sl0 + lg) ^ (q & 7)) << 3)];
#pragma unroll
    for (int df = 0; df < 4; ++df) {
      const int row = df * 16 + lr;
      const bf16x8 vb = *(const bf16x8*)&PsV[row * 256 + (((sl0 + lg) ^ (row & 7)) << 3)];
      accO[df] = __builtin_amdgcn_mfma_f32_16x16x32_bf16(af, vb, accO[df], 0, 0, 0);
    }
  }

  const int growb = (bid >> 3) * 512 + q0 + w * 16 + lg * 4;
#pragma unroll
  for (int df = 0; df < 4; ++df)
#pragma unroll
    for (int r = 0; r < 4; ++r)
      ao16[(size_t)(growb + r) * 512 + h * 64 + df * 16 + lr] = f2b(accO[df][r]);
}

// ---------------- launcher ----------------
extern "C" void kernel_launch(void* const* d_in, const int* in_sizes, int n_in,
                              void* d_out, int out_size, void* d_ws, size_t ws_size,
                              hipStream_t stream) {
  const float* in_f = (const float*)d_in[1];
  const float* in_fkv = (const float*)d_in[2];
  const float* Wq = (const float*)d_in[3];
  const float* Wk = (const float*)d_in[4];
  const float* Wv = (const float*)d_in[5];
  const float* Wz = (const float*)d_in[6];
  const float* bz = (const float*)d_in[7];
  const float* W1 = (const float*)d_in[8];
  const float* b1 = (const float*)d_in[9];
  const float* W2 = (const float*)d_in[10];
  const float* b2 = (const float*)d_in[11];

  float* out_f = (float*)d_out;
  float* attw = out_f + (size_t)MROWS * DDIM;

  const size_t TSB = (size_t)MROWS * DDIM;
  unsigned short* us = (unsigned short*)d_ws;
  unsigned short* a16 = us;
  unsigned short* akv16 = us + TSB;
  unsigned short* q16 = us + 2 * TSB;
  unsigned short* k16 = us + 3 * TSB;
  unsigned short* h16 = us + 4 * TSB;
  unsigned short* ao16 = us + 5 * TSB;
  unsigned short* vT = us + 6 * TSB;
  unsigned short* w16s = us + 7 * TSB;
  float* fbase = (float*)(us + 7 * TSB + 18 * 262144);
  float* p0 = fbase;
  float* p1 = fbase + 4096;
  float* part_q = fbase + 8192;
  float* part_k = fbase + 9216;
  float* corr = fbase + 10240;
  float* sk = fbase + 18432;

  stats_cvt<<<dim3(512, 3), 256, 0, stream>>>(in_f, in_fkv, a16, akv16, p0, p1, Wz, W2, w16s);
  wprep<<<dim3(128, 16), 256, 0, stream>>>(Wq, Wk, Wv, W1, p0, p1, w16s, corr);
  gemm_all<<<dim3(128, 8, 2), 256, 0, stream>>>(a16, akv16, w16s, corr, q16, h16, k16, vT, b1,
                                                part_q, part_k, sk);
  attn_fused<<<2048, 256, 0, stream>>>(q16, k16, vT, part_q, part_k, sk, attw, ao16);
  gemm_final<<<dim3(128, 4), 256, 0, stream>>>(ao16, h16, w16s + 16 * 262144,
                                               w16s + 17 * 262144, out_f, bz, b2, a16);
}